// Round 9
// baseline (318.281 us; speedup 1.0000x reference)
//
#include <hip/hip_runtime.h>

// ---------------------------------------------------------------------------
// VAEAttention: GroupNorm(32) -> q,k,v 1x1 conv -> full spatial attention
// (N=4096 tokens, d=512) -> out proj -> +residual.   B=4, H=W=64, C=512.
// R16: PV re-tiled 128x128 -> 64x128 (split M): grid 512 -> 1024 blocks
// (2 -> 4 blocks/CU), acc halves to f32x16[1][2] (32 VGPR), LDS 24KB dbuf.
// S8 (the 64MB/batch operand) still read exactly once; only vt (8MB/batch,
// L3-resident) re-read.  Core template unchanged (mx32_db<64,128>).
// Everything else identical to R15 (308.9us).
// ---------------------------------------------------------------------------

typedef __bf16 bf16x8 __attribute__((ext_vector_type(8)));
typedef __bf16 bf16x4 __attribute__((ext_vector_type(4)));
typedef float  f32x4  __attribute__((ext_vector_type(4)));
typedef float  f32x16 __attribute__((ext_vector_type(16)));
typedef int    i32x8  __attribute__((ext_vector_type(8)));

#define GLDS(gp, lp) __builtin_amdgcn_global_load_lds( \
    (const __attribute__((address_space(1))) void*)(gp), \
    (__attribute__((address_space(3))) void*)(lp), 16, 0, 0)

// fp32 -> fp8 e4m3 (OCP on gfx950), RNE via HW cvt. Low byte of packed pair.
__device__ __forceinline__ unsigned char f2fp8(float x) {
  int p = __builtin_amdgcn_cvt_pk_fp8_f32(x, 0.f, 0, false);
  return (unsigned char)(p & 0xff);
}

// ---------------------------------------------------------------------------
// GroupNorm stats: one block per (b,g).  64*64 pixels * 16 channels = 65536.
// ---------------------------------------------------------------------------
__global__ __launch_bounds__(256) void k_gnstats(
    const float* __restrict__ x, float* __restrict__ meanv, float* __restrict__ rstdv)
{
  const int bg = blockIdx.x;            // b*32+g
  const int b = bg >> 5, g = bg & 31;
  const float* base = x + (size_t)b * 2097152 + g * 16;
  float s = 0.f, ss = 0.f;
  for (int p = threadIdx.x; p < 4096; p += 256) {
    const float4* rp = (const float4*)(base + (size_t)p * 512);
#pragma unroll
    for (int j = 0; j < 4; ++j) {
      float4 t = rp[j];
      s  += t.x + t.y + t.z + t.w;
      ss += t.x * t.x + t.y * t.y + t.z * t.z + t.w * t.w;
    }
  }
  for (int off = 32; off; off >>= 1) { s += __shfl_xor(s, off, 64); ss += __shfl_xor(ss, off, 64); }
  __shared__ float rs[4], rss[4];
  if ((threadIdx.x & 63) == 0) { rs[threadIdx.x >> 6] = s; rss[threadIdx.x >> 6] = ss; }
  __syncthreads();
  if (threadIdx.x == 0) {
    float S = rs[0] + rs[1] + rs[2] + rs[3];
    float SS = rss[0] + rss[1] + rss[2] + rss[3];
    float m = S * (1.f / 65536.f);
    float var = SS * (1.f / 65536.f) - m * m;
    meanv[bg] = m;
    rstdv[bg] = rsqrtf(var + 1e-6f);
  }
}

// ---------------------------------------------------------------------------
// Normalize + affine + cast to bf16.  8.4M elements, float4 per thread.
// ---------------------------------------------------------------------------
__global__ __launch_bounds__(256) void k_norm(
    const float* __restrict__ x, const float* __restrict__ meanv,
    const float* __restrict__ rstdv, const float* __restrict__ gamma,
    const float* __restrict__ beta, __bf16* __restrict__ x16)
{
  size_t i4 = (size_t)blockIdx.x * 256 + threadIdx.x;  // 0..2097151
  size_t i = i4 * 4;
  int c = (int)(i & 511);
  int bg = (int)(i >> 21) * 32 + (c >> 4);
  float m = meanv[bg], r = rstdv[bg];
  float4 xv = *(const float4*)(x + i);
  float4 gv = *(const float4*)(gamma + c);
  float4 bv = *(const float4*)(beta + c);
  bf16x4 o;
  o[0] = (__bf16)((xv.x - m) * r * gv.x + bv.x);
  o[1] = (__bf16)((xv.y - m) * r * gv.y + bv.y);
  o[2] = (__bf16)((xv.z - m) * r * gv.z + bv.z);
  o[3] = (__bf16)((xv.w - m) * r * gv.w + bv.w);
  *(bf16x4*)(x16 + i) = o;
}

// ---------------------------------------------------------------------------
// Weight prep: Bt layouts (row = output dim, contiguous K).
// wqkvt[1536][512] (wq scaled by 1/sqrt(512)), biasqkv[1536], wot[512][512].
// Also zeroes the row-sum buffer l[16384] (tail of index range).
// ---------------------------------------------------------------------------
__global__ __launch_bounds__(256) void k_prep(
    const float* __restrict__ wq, const float* __restrict__ bq,
    const float* __restrict__ wk, const float* __restrict__ bk,
    const float* __restrict__ wv, const float* __restrict__ bv,
    const float* __restrict__ wo,
    __bf16* __restrict__ wqkvt, float* __restrict__ biasqkv, __bf16* __restrict__ wot,
    float* __restrict__ lsum)
{
  const float sc = 0.04419417382415922f;  // 1/sqrt(512)
  int idx = blockIdx.x * 256 + threadIdx.x;
  if (idx < 786432) {
    int d = idx >> 9, c = idx & 511;
    float v;
    if (d < 512)       v = wq[c * 512 + d] * sc;
    else if (d < 1024) v = wk[c * 512 + d - 512];
    else               v = wv[c * 512 + d - 1024];
    wqkvt[idx] = (__bf16)v;
  } else if (idx < 786432 + 262144) {
    int j = idx - 786432;
    int d = j >> 9, c = j & 511;
    wot[j] = (__bf16)wo[c * 512 + d];
  } else if (idx < 786432 + 262144 + 1536) {
    int d = idx - 786432 - 262144;
    float v = (d < 512) ? bq[d] * sc : (d < 1024 ? bk[d - 512] : bv[d - 1024]);
    biasqkv[d] = v;
  } else if (idx < 786432 + 262144 + 1536 + 16384) {
    lsum[idx - 786432 - 262144 - 1536] = 0.f;
  }
}

// ---------------------------------------------------------------------------
// GEMM core (bf16, XOR-swizzled LDS, 2-phase double-buffer):
// prologue stages tile 0; per tile: STAGE(t+1) -> ds_read+MFMA(t) -> ONE
// barrier (R14-verified).
// ---------------------------------------------------------------------------
template <int BM, int BN>
__device__ __forceinline__ void gemm_core_db(
    const __bf16* __restrict__ A, const __bf16* __restrict__ Bt, int K,
    int m0, int n0, __bf16* smem, f32x4 (&acc)[BM / 32][BN / 32])
{
  constexpr int FM = BM / 32, FN = BN / 32;
  constexpr int ASZ = BM * 32;          // elements per A tile (BM x 32)
  constexpr int BSZ = BN * 32;
  constexpr int BUF = ASZ + BSZ;
  const int tid = threadIdx.x;
  const int lane = tid & 63;
  const int wave = tid >> 6;
  const int wm = wave >> 1, wn = wave & 1;
  const int l15 = lane & 15, l4 = lane >> 4;
  const int sw = (l15 >> 1) & 3;            // read-side chunk swizzle
  const int nt = K >> 5;

  auto stage = [&](int b, int kt) {
    __bf16* As_ = smem + b * BUF;
    __bf16* Bs_ = As_ + ASZ;
#pragma unroll
    for (int i = 0; i < BM / 64; ++i) {
      int ci = i * 256 + tid;
      int row = ci >> 2, kc = ci & 3;
      int kcs = kc ^ ((row >> 1) & 3);       // swizzled source chunk
      GLDS(A + (size_t)(m0 + row) * K + kt + kcs * 8, As_ + i * 2048 + wave * 512);
    }
#pragma unroll
    for (int i = 0; i < BN / 64; ++i) {
      int ci = i * 256 + tid;
      int row = ci >> 2, kc = ci & 3;
      int kcs = kc ^ ((row >> 1) & 3);
      GLDS(Bt + (size_t)(n0 + row) * K + kt + kcs * 8, Bs_ + i * 2048 + wave * 512);
    }
  };

  stage(0, 0);
  __syncthreads();                       // tile 0 valid
  for (int t = 0; t < nt; ++t) {
    if (t + 1 < nt) stage((t + 1) & 1, (t + 1) * 32);
    const __bf16* As = smem + (t & 1) * BUF;
    const __bf16* Bs = As + ASZ;
    bf16x8 af[FM], bfr[FN];
#pragma unroll
    for (int mi = 0; mi < FM; ++mi)
      af[mi] = *(const bf16x8*)&As[(wm * (BM / 2) + mi * 16 + l15) * 32 + (l4 ^ sw) * 8];
#pragma unroll
    for (int ni = 0; ni < FN; ++ni)
      bfr[ni] = *(const bf16x8*)&Bs[(wn * (BN / 2) + ni * 16 + l15) * 32 + (l4 ^ sw) * 8];
#pragma unroll
    for (int mi = 0; mi < FM; ++mi)
#pragma unroll
      for (int ni = 0; ni < FN; ++ni)
        acc[mi][ni] = __builtin_amdgcn_mfma_f32_16x16x32_bf16(af[mi], bfr[ni], acc[mi][ni], 0, 0, 0);
    __syncthreads();  // t+1 loads drained; buf[t&1] reads done before overwrite
  }
}

// ---------------------------------------------------------------------------
// GEMM core (fp8 x fp8, BK=64, XOR-swizzled, 2-phase double-buffer):
// R12/R14-verified (VGPR 80-84 on k_gemm_s).
// ---------------------------------------------------------------------------
template <int BM, int BN>
__device__ __forceinline__ void gemm_core_fp8_db(
    const unsigned char* __restrict__ A, const unsigned char* __restrict__ Bt,
    int K, int m0, int n0, unsigned char* smem,
    f32x4 (&acc)[BM / 32][BN / 32])
{
  constexpr int FM = BM / 32, FN = BN / 32;
  constexpr int ASZ = (BM / 64) * 4096;   // A tile bytes (BM x 64)
  constexpr int BSZ = (BN / 64) * 4096;
  constexpr int BUF = ASZ + BSZ;
  const int tid = threadIdx.x;
  const int lane = tid & 63;
  const int wave = tid >> 6;
  const int wm = wave >> 1, wn = wave & 1;
  const int l15 = lane & 15, l4 = lane >> 4;
  const int sw = (l15 >> 1) & 3;
  const int h8 = (l4 & 1) * 8;      // 8B half within a 16B chunk
  const int nt = K >> 6;

  auto stage = [&](int b, int kt) {
    unsigned char* As_ = smem + b * BUF;
    unsigned char* Bs_ = As_ + ASZ;
#pragma unroll
    for (int i = 0; i < BM / 64; ++i) {
      int ci = i * 256 + tid;
      int row = ci >> 2, kc = ci & 3;
      int kcs = (kc ^ ((row >> 1) & 3)) * 16;  // swizzled 16B source chunk
      GLDS(A + (size_t)(m0 + row) * K + kt + kcs, As_ + i * 4096 + wave * 1024);
    }
#pragma unroll
    for (int i = 0; i < BN / 64; ++i) {
      int ci = i * 256 + tid;
      int row = ci >> 2, kc = ci & 3;
      int kcs = (kc ^ ((row >> 1) & 3)) * 16;
      GLDS(Bt + (size_t)(n0 + row) * K + kt + kcs, Bs_ + i * 4096 + wave * 1024);
    }
  };

  stage(0, 0);
  __syncthreads();                       // tile 0 valid
  for (int t = 0; t < nt; ++t) {
    if (t + 1 < nt) stage((t + 1) & 1, (t + 1) * 64);
    const unsigned char* As = smem + (t & 1) * BUF;
    const unsigned char* Bs = As + ASZ;
    long long af[FM][2], bfr[FN][2];
#pragma unroll
    for (int mi = 0; mi < FM; ++mi) {
      int row = wm * (BM / 2) + mi * 16 + l15;
#pragma unroll
      for (int j = 0; j < 2; ++j) {
        int G = j * 2 + (l4 >> 1);           // global 16B-chunk index
        af[mi][j] = *(const long long*)&As[row * 64 + ((G ^ sw) << 4) + h8];
      }
    }
#pragma unroll
    for (int ni = 0; ni < FN; ++ni) {
      int row = wn * (BN / 2) + ni * 16 + l15;
#pragma unroll
      for (int j = 0; j < 2; ++j) {
        int G = j * 2 + (l4 >> 1);
        bfr[ni][j] = *(const long long*)&Bs[row * 64 + ((G ^ sw) << 4) + h8];
      }
    }
#pragma unroll
    for (int mi = 0; mi < FM; ++mi)
#pragma unroll
      for (int ni = 0; ni < FN; ++ni) {
        f32x4 c = acc[mi][ni];
        c = __builtin_amdgcn_mfma_f32_16x16x32_fp8_fp8(af[mi][0], bfr[ni][0], c, 0, 0, 0);
        c = __builtin_amdgcn_mfma_f32_16x16x32_fp8_fp8(af[mi][1], bfr[ni][1], c, 0, 0, 0);
        acc[mi][ni] = c;
      }
    __syncthreads();  // t+1 loads drained; buf[t&1] reads done before overwrite
  }
}

// ---------------------------------------------------------------------------
// GEMM core (MX fp8, 32x32x64, scale=1.0, 2-phase double-buffer): PV only.
// A-operand: lane l holds row (l&31), k-bytes [ (l>>5)*32 , +32 ).
// C/D (m74/m101): col = lane&31, row = (r&3)+8*(r>>2)+4*(l>>5).
// Generic in BM/BN (wave grid 2x2; per-wave patch (BM/2)x(BN/2)).
// ---------------------------------------------------------------------------
template <int BM, int BN>
__device__ __forceinline__ void gemm_core_mx32_db(
    const unsigned char* __restrict__ A, const unsigned char* __restrict__ Bt,
    int K, int m0, int n0, unsigned char* smem,
    f32x16 (&acc)[BM / 64][BN / 64])
{
  constexpr int FM = BM / 64, FN = BN / 64;
  constexpr int ASZ = (BM / 64) * 4096;
  constexpr int BSZ = (BN / 64) * 4096;
  constexpr int BUF = ASZ + BSZ;
  const int tid = threadIdx.x;
  const int lane = tid & 63;
  const int wave = tid >> 6;
  const int wm = wave >> 1, wn = wave & 1;
  const int l31 = lane & 31, h = lane >> 5;   // h: k-block of 32 bytes
  const int nt = K >> 6;

  auto stage = [&](int b, int kt) {
    unsigned char* As_ = smem + b * BUF;
    unsigned char* Bs_ = As_ + ASZ;
#pragma unroll
    for (int i = 0; i < BM / 64; ++i) {
      int ci = i * 256 + tid;
      int row = ci >> 2, kc = ci & 3;
      int kcs = (kc ^ ((row >> 1) & 3)) * 16;
      GLDS(A + (size_t)(m0 + row) * K + kt + kcs, As_ + i * 4096 + wave * 1024);
    }
#pragma unroll
    for (int i = 0; i < BN / 64; ++i) {
      int ci = i * 256 + tid;
      int row = ci >> 2, kc = ci & 3;
      int kcs = (kc ^ ((row >> 1) & 3)) * 16;
      GLDS(Bt + (size_t)(n0 + row) * K + kt + kcs, Bs_ + i * 4096 + wave * 1024);
    }
  };

  stage(0, 0);
  __syncthreads();
  for (int t = 0; t < nt; ++t) {
    if (t + 1 < nt) stage((t + 1) & 1, (t + 1) * 64);
    const unsigned char* As = smem + (t & 1) * BUF;
    const unsigned char* Bs = As + ASZ;
    i32x8 af[FM], bfr[FN];
#pragma unroll
    for (int mi = 0; mi < FM; ++mi) {
      int row = wm * (BM / 2) + mi * 32 + l31;
      int s = (row >> 1) & 3;
      int c0 = (2 * h) ^ s, c1 = (2 * h + 1) ^ s;   // two 16B chunks = 32B of k
      uint4 u0 = *(const uint4*)&As[row * 64 + c0 * 16];
      uint4 u1 = *(const uint4*)&As[row * 64 + c1 * 16];
      af[mi][0] = (int)u0.x; af[mi][1] = (int)u0.y; af[mi][2] = (int)u0.z; af[mi][3] = (int)u0.w;
      af[mi][4] = (int)u1.x; af[mi][5] = (int)u1.y; af[mi][6] = (int)u1.z; af[mi][7] = (int)u1.w;
    }
#pragma unroll
    for (int ni = 0; ni < FN; ++ni) {
      int row = wn * (BN / 2) + ni * 32 + l31;
      int s = (row >> 1) & 3;
      int c0 = (2 * h) ^ s, c1 = (2 * h + 1) ^ s;
      uint4 u0 = *(const uint4*)&Bs[row * 64 + c0 * 16];
      uint4 u1 = *(const uint4*)&Bs[row * 64 + c1 * 16];
      bfr[ni][0] = (int)u0.x; bfr[ni][1] = (int)u0.y; bfr[ni][2] = (int)u0.z; bfr[ni][3] = (int)u0.w;
      bfr[ni][4] = (int)u1.x; bfr[ni][5] = (int)u1.y; bfr[ni][6] = (int)u1.z; bfr[ni][7] = (int)u1.w;
    }
#pragma unroll
    for (int mi = 0; mi < FM; ++mi)
#pragma unroll
      for (int ni = 0; ni < FN; ++ni)
        acc[mi][ni] = __builtin_amdgcn_mfma_scale_f32_32x32x64_f8f6f4(
            af[mi], bfr[ni], acc[mi][ni],
            0, 0,                       // cbsz/blgp = fp8 e4m3
            0, 0x7f7f7f7f,              // scale_a: e8m0 = 1.0
            0, 0x7f7f7f7f);             // scale_b: e8m0 = 1.0
    __syncthreads();
  }
}

// fp8 16x16 C/D layout (measured m89/m91): col = lane&15, row = (lane>>4)*4 + reg.

// ---------------------------------------------------------------------------
// QKV GEMM: X[16384][512] @ Wqkv^T.  All outputs staged in LDS and written
// as coalesced 16B chunks: q8/k8 as [token][c] rows, v transposed to
// vt8[b][c][n] rows.  Bias folded into the staging conversion.  (R15-verified)
// ---------------------------------------------------------------------------
__global__ __launch_bounds__(256) void k_gemm_qkv(
    const __bf16* __restrict__ X, const __bf16* __restrict__ Wt,
    const float* __restrict__ bias, unsigned char* __restrict__ q8,
    unsigned char* __restrict__ k8, unsigned char* __restrict__ vt8)
{
  __shared__ __align__(16) __bf16 smem[2 * (128 * 32 + 128 * 32)];  // 32 KB dbuf
  f32x4 acc[4][4];
#pragma unroll
  for (int i = 0; i < 4; ++i)
#pragma unroll
    for (int j = 0; j < 4; ++j)
#pragma unroll
      for (int r = 0; r < 4; ++r) acc[i][j][r] = 0.f;
  const int m0 = blockIdx.x * 128, n0 = blockIdx.y * 128;
  gemm_core_db<128, 128>(X, Wt, 512, m0, n0, smem, acc);

  const int lane = threadIdx.x & 63, wave = threadIdx.x >> 6;
  const int wm = wave >> 1, wn = wave & 1, l15 = lane & 15, l4 = lane >> 4;

  // Stage the 128x128 fp8 patch in LDS (stride 144), then store coalesced.
  unsigned char* t8 = (unsigned char*)smem;  // 128*144 = 18432 B <= 32768
  if (blockIdx.y < 8) {
    // q or k: patch[token_local][c_local], no transpose
#pragma unroll
    for (int mi = 0; mi < 4; ++mi)
#pragma unroll
      for (int ni = 0; ni < 4; ++ni) {
        int lcol = wn * 64 + ni * 16 + l15;
        float bb = bias[n0 + lcol];
#pragma unroll
        for (int r = 0; r < 4; ++r) {
          int lrow = wm * 64 + mi * 16 + l4 * 4 + r;
          t8[lrow * 144 + lcol] = f2fp8(acc[mi][ni][r] + bb);
        }
      }
    __syncthreads();
    unsigned char* dst = (blockIdx.y < 4) ? q8 : k8;
    const int c0 = (blockIdx.y < 4) ? n0 : n0 - 512;
#pragma unroll
    for (int j = 0; j < 4; ++j) {
      int idx = j * 256 + threadIdx.x;
      int crow = idx >> 3, ccol = (idx & 7) * 16;
      uint4 v = *(const uint4*)&t8[crow * 144 + ccol];
      *(uint4*)&dst[(size_t)(m0 + crow) * 512 + c0 + ccol] = v;
    }
  } else {
    // v: patch transposed to [c_local][token_local]
#pragma unroll
    for (int mi = 0; mi < 4; ++mi)
#pragma unroll
      for (int ni = 0; ni < 4; ++ni) {
        int c_l = wn * 64 + ni * 16 + l15;
        float bb = bias[n0 + c_l];
#pragma unroll
        for (int r = 0; r < 4; ++r) {
          int n_l = wm * 64 + mi * 16 + l4 * 4 + r;
          t8[c_l * 144 + n_l] = f2fp8(acc[mi][ni][r] + bb);
        }
      }
    __syncthreads();
    const int b = m0 >> 12, nst = m0 & 4095;
    const int c0 = n0 - 1024;
#pragma unroll
    for (int j = 0; j < 4; ++j) {
      int idx = j * 256 + threadIdx.x;
      int crow = idx >> 3, ccol = (idx & 7) * 16;
      uint4 v = *(const uint4*)&t8[crow * 144 + ccol];
      *(uint4*)&vt8[((size_t)b * 512 + c0 + crow) * 4096 + nst + ccol] = v;
    }
  }
}

// ---------------------------------------------------------------------------
// Scores GEMM (fp8 x fp8, BK=64, 2-phase dbuf) + max-free softmax numerator,
// batched over z: P[b][n][m] = exp(q.k) stored fp8 e4m3; lsum fp32 row sums.
// Epilogue: exp+rowsum in regs, ONE-pass staging into 128x144 LDS tile,
// 16B-coalesced stores.  (R15-verified: 81.5us, VGPR 80.)
// ---------------------------------------------------------------------------
__global__ __launch_bounds__(256) void k_gemm_s(
    const unsigned char* __restrict__ qall, const unsigned char* __restrict__ kall,
    unsigned char* __restrict__ S8all, float* __restrict__ lsum)
{
  __shared__ __align__(16) unsigned char smem[32768];  // 2 x (8KB As + 8KB Bs)
  f32x4 acc[4][4];
#pragma unroll
  for (int i = 0; i < 4; ++i)
#pragma unroll
    for (int j = 0; j < 4; ++j)
#pragma unroll
      for (int r = 0; r < 4; ++r) acc[i][j][r] = 0.f;

  // supertile swizzle: 1024 blocks/batch -> 16 groups of 64 (8x8)
  const int b = blockIdx.z;
  const int flat = blockIdx.x + (blockIdx.y << 5);
  const int gx = flat & 7, gy = (flat >> 3) & 7, grp = flat >> 6;
  const int bx = (grp & 3) * 8 + gx, by = (grp >> 2) * 8 + gy;
  const int m0 = bx * 128, n0 = by * 128;

  const unsigned char* q = qall + (size_t)b * 4096 * 512;
  const unsigned char* k = kall + (size_t)b * 4096 * 512;
  unsigned char* S8 = S8all + (size_t)b * 4096 * 4096;
  gemm_core_fp8_db<128, 128>(q, k, 512, m0, n0, smem, acc);

  const int lane = threadIdx.x & 63, wave = threadIdx.x >> 6;
  const int wm = wave >> 1, wn = wave & 1, l15 = lane & 15, l4 = lane >> 4;

  // exp in place + fp32 row-sum atomics (pre-fp8-rounding; unbiased)
#pragma unroll
  for (int mi = 0; mi < 4; ++mi) {
    float rsum[4] = {0.f, 0.f, 0.f, 0.f};
#pragma unroll
    for (int ni = 0; ni < 4; ++ni)
#pragma unroll
      for (int r = 0; r < 4; ++r) {
        float p = __expf(acc[mi][ni][r]);
        acc[mi][ni][r] = p;
        rsum[r] += p;
      }
#pragma unroll
    for (int r = 0; r < 4; ++r) {
#pragma unroll
      for (int off = 1; off < 16; off <<= 1) rsum[r] += __shfl_xor(rsum[r], off, 64);
      if (l15 == 0) {
        int grow = m0 + wm * 64 + mi * 16 + l4 * 4 + r;
        atomicAdd(&lsum[b * 4096 + grow], rsum[r]);
      }
    }
  }

  // One-pass staging: all waves convert into t8[128][144], then store.
  unsigned char* t8 = smem;  // 128*144 = 18432 B <= 32768
#pragma unroll
  for (int mi = 0; mi < 4; ++mi)
#pragma unroll
    for (int ni = 0; ni < 4; ++ni) {
      int lcol = wn * 64 + ni * 16 + l15;
#pragma unroll
      for (int r = 0; r < 4; ++r) {
        int lrow = wm * 64 + mi * 16 + l4 * 4 + r;
        t8[lrow * 144 + lcol] = f2fp8(acc[mi][ni][r]);
      }
    }
  __syncthreads();
  // store 128 rows x 128 B: 1024 chunks of 16B, 4 per thread
#pragma unroll
  for (int j = 0; j < 4; ++j) {
    int idx = j * 256 + threadIdx.x;
    int crow = idx >> 3, ccol = (idx & 7) * 16;
    uint4 v = *(const uint4*)&t8[crow * 144 + ccol];
    *(uint4*)&S8[(size_t)(m0 + crow) * 4096 + n0 + ccol] = v;
  }
}

// ---------------------------------------------------------------------------
// PV GEMM (MX fp8 32x32x64, BK=64, 2-phase dbuf, 64x128 tile), batched over z:
// O[b,n,c] = (sum_m P[b,n,m] * vt[b,c,m]) / l[b,n].
// Grid (64, 4, 4) = 1024 blocks -> 4 blocks/CU.  acc = f32x16[1][2].
// ---------------------------------------------------------------------------
__global__ __launch_bounds__(256) void k_gemm_pv(
    const unsigned char* __restrict__ S8all, const unsigned char* __restrict__ vt8all,
    const float* __restrict__ lsum, __bf16* __restrict__ attn)
{
  __shared__ __align__(16) unsigned char smem[24576];  // 2 x (4KB As + 8KB Bs)
  f32x16 acc[1][2];
#pragma unroll
  for (int j = 0; j < 2; ++j)
#pragma unroll
    for (int r = 0; r < 16; ++r) acc[0][j][r] = 0.f;
  const int b = blockIdx.z;
  const unsigned char* P = S8all + (size_t)b * 4096 * 4096;
  const unsigned char* V = vt8all + (size_t)b * 512 * 4096;
  __bf16* O = attn + (size_t)b * 4096 * 512;
  const int m0 = blockIdx.x * 64, n0 = blockIdx.y * 128;
  gemm_core_mx32_db<64, 128>(P, V, 4096, m0, n0, smem, acc);

  const int lane = threadIdx.x & 63, wave = threadIdx.x >> 6;
  const int wm = wave >> 1, wn = wave & 1, l31 = lane & 31, h = lane >> 5;
#pragma unroll
  for (int ni = 0; ni < 2; ++ni) {
    int gcol = n0 + wn * 64 + ni * 32 + l31;
#pragma unroll
    for (int r = 0; r < 16; ++r) {
      int grow = m0 + wm * 32 + (r & 3) + 8 * (r >> 2) + 4 * h;
      float inv = 1.f / lsum[b * 4096 + grow];
      O[(size_t)grow * 512 + gcol] = (__bf16)(acc[0][ni][r] * inv);
    }
  }
}

// ---------------------------------------------------------------------------
// Output projection + bias + residual, fp32 store to d_out.
// ---------------------------------------------------------------------------
__global__ __launch_bounds__(256) void k_gemm_out(
    const __bf16* __restrict__ A, const __bf16* __restrict__ Wot,
    const float* __restrict__ bo, const float* __restrict__ resid, float* __restrict__ out)
{
  __shared__ __align__(16) __bf16 smem[2 * (128 * 32 + 128 * 32)];  // 32 KB dbuf
  f32x4 acc[4][4];
#pragma unroll
  for (int i = 0; i < 4; ++i)
#pragma unroll
    for (int j = 0; j < 4; ++j)
#pragma unroll
      for (int r = 0; r < 4; ++r) acc[i][j][r] = 0.f;
  const int m0 = blockIdx.x * 128, n0 = blockIdx.y * 128;
  gemm_core_db<128, 128>(A, Wot, 512, m0, n0, smem, acc);

  const int lane = threadIdx.x & 63, wave = threadIdx.x >> 6;
  const int wm = wave >> 1, wn = wave & 1, l15 = lane & 15, l4 = lane >> 4;
#pragma unroll
  for (int mi = 0; mi < 4; ++mi)
#pragma unroll
    for (int ni = 0; ni < 4; ++ni) {
      int gcol = n0 + wn * 64 + ni * 16 + l15;
      float bb = bo[gcol];
#pragma unroll
      for (int r = 0; r < 4; ++r) {
        int grow = m0 + wm * 64 + mi * 16 + l4 * 4 + r;
        size_t idx = (size_t)grow * 512 + gcol;
        out[idx] = acc[mi][ni][r] + bb + resid[idx];
      }
    }
}

// ---------------------------------------------------------------------------
extern "C" void kernel_launch(void* const* d_in, const int* in_sizes, int n_in,
                              void* d_out, int out_size, void* d_ws, size_t ws_size,
                              hipStream_t stream)
{
  const float* x     = (const float*)d_in[0];
  const float* gamma = (const float*)d_in[1];
  const float* beta  = (const float*)d_in[2];
  const float* wq    = (const float*)d_in[3];
  const float* bq    = (const float*)d_in[4];
  const float* wk    = (const float*)d_in[5];
  const float* bk    = (const float*)d_in[6];
  const float* wv    = (const float*)d_in[7];
  const float* bv    = (const float*)d_in[8];
  const float* wo    = (const float*)d_in[9];
  const float* bo    = (const float*)d_in[10];
  float* out = (float*)d_out;

  char* ws = (char*)d_ws;
  size_t off = 0;
  auto alloc = [&](size_t bytes) -> char* {
    char* p = ws + off;
    off += (bytes + 255) & ~(size_t)255;
    return p;
  };
  float*  meanv   = (float*)alloc(128 * 4);
  float*  rstdv   = (float*)alloc(128 * 4);
  __bf16* x16     = (__bf16*)alloc(16384ull * 512 * 2);   // 16 MB
  __bf16* wqkvt   = (__bf16*)alloc(1536ull * 512 * 2);    // 1.5 MB
  float*  biasqkv = (float*)alloc(1536 * 4);
  __bf16* wot     = (__bf16*)alloc(512ull * 512 * 2);     // 0.5 MB
  float*  lsum    = (float*)alloc(16384ull * 4);          // 64 KB row sums
  unsigned char* q8  = (unsigned char*)alloc(16384ull * 512);     // 8 MB fp8 Q
  unsigned char* k8  = (unsigned char*)alloc(16384ull * 512);     // 8 MB fp8 K
  unsigned char* vt8 = (unsigned char*)alloc(16384ull * 512);     // 8 MB fp8 V^T
  __bf16* attn    = (__bf16*)alloc(16384ull * 512 * 2);   // 16 MB
  unsigned char* S8 = (unsigned char*)alloc(4ull * 4096 * 4096);  // 64 MB fp8 exp(scores)
  // total ~122 MB

  k_gnstats<<<dim3(128), dim3(256), 0, stream>>>(x, meanv, rstdv);
  k_norm<<<dim3(8192), dim3(256), 0, stream>>>(x, meanv, rstdv, gamma, beta, x16);
  k_prep<<<dim3(4166), dim3(256), 0, stream>>>(wq, bq, wk, bk, wv, bv, wo,
                                               wqkvt, biasqkv, wot, lsum);
  k_gemm_qkv<<<dim3(128, 12), dim3(256), 0, stream>>>(x16, wqkvt, biasqkv, q8, k8, vt8);
  k_gemm_s<<<dim3(32, 32, 4), dim3(256), 0, stream>>>(q8, k8, S8, lsum);
  k_gemm_pv<<<dim3(64, 4, 4), dim3(256), 0, stream>>>(S8, vt8, lsum, attn);
  k_gemm_out<<<dim3(128, 4), dim3(256), 0, stream>>>(attn, wot, bo, x, out);
}

// Round 11
// 297.427 us; speedup vs baseline: 1.0701x; 1.0701x over previous
//
#include <hip/hip_runtime.h>

// ---------------------------------------------------------------------------
// VAEAttention: GroupNorm(32) -> q,k,v 1x1 conv -> full spatial attention
// (N=4096 tokens, d=512) -> out proj -> +residual.   B=4, H=W=64, C=512.
// R17 (resubmit; previous round was an infra failure, not a kernel failure):
// PV at R15's 128x128 mx32_db.  k_gnstats parallelized 128 -> 1024 blocks
// (8 chunks per (b,g), atomicAdd partial sums into gns/gnss zeroed by
// k_prep, which launches first); k_norm finalizes mean/rstd inline.
// ---------------------------------------------------------------------------

typedef __bf16 bf16x8 __attribute__((ext_vector_type(8)));
typedef __bf16 bf16x4 __attribute__((ext_vector_type(4)));
typedef float  f32x4  __attribute__((ext_vector_type(4)));
typedef float  f32x16 __attribute__((ext_vector_type(16)));
typedef int    i32x8  __attribute__((ext_vector_type(8)));

#define GLDS(gp, lp) __builtin_amdgcn_global_load_lds( \
    (const __attribute__((address_space(1))) void*)(gp), \
    (__attribute__((address_space(3))) void*)(lp), 16, 0, 0)

// fp32 -> fp8 e4m3 (OCP on gfx950), RNE via HW cvt. Low byte of packed pair.
__device__ __forceinline__ unsigned char f2fp8(float x) {
  int p = __builtin_amdgcn_cvt_pk_fp8_f32(x, 0.f, 0, false);
  return (unsigned char)(p & 0xff);
}

// ---------------------------------------------------------------------------
// GroupNorm partial stats: 1024 blocks = 8 chunks per (b,g).  Each block
// reduces 512 pixels x 16 channels = 32KB and atomicAdds (s, ss) into
// gns/gnss[128] (zeroed by k_prep, launched before this).
// ---------------------------------------------------------------------------
__global__ __launch_bounds__(256) void k_gnstats(
    const float* __restrict__ x, float* __restrict__ gns, float* __restrict__ gnss)
{
  const int blk = blockIdx.x;           // 0..1023
  const int bg = blk >> 3, chunk = blk & 7;
  const int b = bg >> 5, g = bg & 31;
  const float* base = x + (size_t)b * 2097152 + g * 16;
  float s = 0.f, ss = 0.f;
#pragma unroll
  for (int it = 0; it < 2; ++it) {
    int p = chunk * 512 + it * 256 + threadIdx.x;
    const float4* rp = (const float4*)(base + (size_t)p * 512);
#pragma unroll
    for (int j = 0; j < 4; ++j) {
      float4 t = rp[j];
      s  += t.x + t.y + t.z + t.w;
      ss += t.x * t.x + t.y * t.y + t.z * t.z + t.w * t.w;
    }
  }
  for (int off = 32; off; off >>= 1) { s += __shfl_xor(s, off, 64); ss += __shfl_xor(ss, off, 64); }
  __shared__ float rs[4], rss[4];
  if ((threadIdx.x & 63) == 0) { rs[threadIdx.x >> 6] = s; rss[threadIdx.x >> 6] = ss; }
  __syncthreads();
  if (threadIdx.x == 0) {
    atomicAdd(&gns[bg],  rs[0] + rs[1] + rs[2] + rs[3]);
    atomicAdd(&gnss[bg], rss[0] + rss[1] + rss[2] + rss[3]);
  }
}

// ---------------------------------------------------------------------------
// Normalize + affine + cast to bf16; finalizes mean/rstd from (s, ss).
// ---------------------------------------------------------------------------
__global__ __launch_bounds__(256) void k_norm(
    const float* __restrict__ x, const float* __restrict__ gns,
    const float* __restrict__ gnss, const float* __restrict__ gamma,
    const float* __restrict__ beta, __bf16* __restrict__ x16)
{
  size_t i4 = (size_t)blockIdx.x * 256 + threadIdx.x;  // 0..2097151
  size_t i = i4 * 4;
  int c = (int)(i & 511);
  int bg = (int)(i >> 21) * 32 + (c >> 4);
  float s = gns[bg], ss = gnss[bg];
  float m = s * (1.f / 65536.f);
  float var = ss * (1.f / 65536.f) - m * m;
  float r = rsqrtf(var + 1e-6f);
  float4 xv = *(const float4*)(x + i);
  float4 gv = *(const float4*)(gamma + c);
  float4 bv = *(const float4*)(beta + c);
  bf16x4 o;
  o[0] = (__bf16)((xv.x - m) * r * gv.x + bv.x);
  o[1] = (__bf16)((xv.y - m) * r * gv.y + bv.y);
  o[2] = (__bf16)((xv.z - m) * r * gv.z + bv.z);
  o[3] = (__bf16)((xv.w - m) * r * gv.w + bv.w);
  *(bf16x4*)(x16 + i) = o;
}

// ---------------------------------------------------------------------------
// Weight prep: Bt layouts (row = output dim, contiguous K).
// wqkvt[1536][512] (wq scaled by 1/sqrt(512)), biasqkv[1536], wot[512][512].
// Also zeroes lsum[16384] and the GN stat buffers gns/gnss[128] (tail).
// ---------------------------------------------------------------------------
__global__ __launch_bounds__(256) void k_prep(
    const float* __restrict__ wq, const float* __restrict__ bq,
    const float* __restrict__ wk, const float* __restrict__ bk,
    const float* __restrict__ wv, const float* __restrict__ bv,
    const float* __restrict__ wo,
    __bf16* __restrict__ wqkvt, float* __restrict__ biasqkv, __bf16* __restrict__ wot,
    float* __restrict__ lsum, float* __restrict__ gns, float* __restrict__ gnss)
{
  const float sc = 0.04419417382415922f;  // 1/sqrt(512)
  int idx = blockIdx.x * 256 + threadIdx.x;
  if (idx < 786432) {
    int d = idx >> 9, c = idx & 511;
    float v;
    if (d < 512)       v = wq[c * 512 + d] * sc;
    else if (d < 1024) v = wk[c * 512 + d - 512];
    else               v = wv[c * 512 + d - 1024];
    wqkvt[idx] = (__bf16)v;
  } else if (idx < 786432 + 262144) {
    int j = idx - 786432;
    int d = j >> 9, c = j & 511;
    wot[j] = (__bf16)wo[c * 512 + d];
  } else if (idx < 786432 + 262144 + 1536) {
    int d = idx - 786432 - 262144;
    float v = (d < 512) ? bq[d] * sc : (d < 1024 ? bk[d - 512] : bv[d - 1024]);
    biasqkv[d] = v;
  } else if (idx < 786432 + 262144 + 1536 + 16384) {
    lsum[idx - 786432 - 262144 - 1536] = 0.f;
  } else if (idx < 786432 + 262144 + 1536 + 16384 + 256) {
    int j = idx - 786432 - 262144 - 1536 - 16384;
    if (j < 128) gns[j] = 0.f; else gnss[j - 128] = 0.f;
  }
}

// ---------------------------------------------------------------------------
// GEMM core (bf16, XOR-swizzled LDS, 2-phase double-buffer):
// prologue stages tile 0; per tile: STAGE(t+1) -> ds_read+MFMA(t) -> ONE
// barrier (R14-verified).
// ---------------------------------------------------------------------------
template <int BM, int BN>
__device__ __forceinline__ void gemm_core_db(
    const __bf16* __restrict__ A, const __bf16* __restrict__ Bt, int K,
    int m0, int n0, __bf16* smem, f32x4 (&acc)[BM / 32][BN / 32])
{
  constexpr int FM = BM / 32, FN = BN / 32;
  constexpr int ASZ = BM * 32;          // elements per A tile (BM x 32)
  constexpr int BSZ = BN * 32;
  constexpr int BUF = ASZ + BSZ;
  const int tid = threadIdx.x;
  const int lane = tid & 63;
  const int wave = tid >> 6;
  const int wm = wave >> 1, wn = wave & 1;
  const int l15 = lane & 15, l4 = lane >> 4;
  const int sw = (l15 >> 1) & 3;            // read-side chunk swizzle
  const int nt = K >> 5;

  auto stage = [&](int b, int kt) {
    __bf16* As_ = smem + b * BUF;
    __bf16* Bs_ = As_ + ASZ;
#pragma unroll
    for (int i = 0; i < BM / 64; ++i) {
      int ci = i * 256 + tid;
      int row = ci >> 2, kc = ci & 3;
      int kcs = kc ^ ((row >> 1) & 3);       // swizzled source chunk
      GLDS(A + (size_t)(m0 + row) * K + kt + kcs * 8, As_ + i * 2048 + wave * 512);
    }
#pragma unroll
    for (int i = 0; i < BN / 64; ++i) {
      int ci = i * 256 + tid;
      int row = ci >> 2, kc = ci & 3;
      int kcs = kc ^ ((row >> 1) & 3);
      GLDS(Bt + (size_t)(n0 + row) * K + kt + kcs * 8, Bs_ + i * 2048 + wave * 512);
    }
  };

  stage(0, 0);
  __syncthreads();                       // tile 0 valid
  for (int t = 0; t < nt; ++t) {
    if (t + 1 < nt) stage((t + 1) & 1, (t + 1) * 32);
    const __bf16* As = smem + (t & 1) * BUF;
    const __bf16* Bs = As + ASZ;
    bf16x8 af[FM], bfr[FN];
#pragma unroll
    for (int mi = 0; mi < FM; ++mi)
      af[mi] = *(const bf16x8*)&As[(wm * (BM / 2) + mi * 16 + l15) * 32 + (l4 ^ sw) * 8];
#pragma unroll
    for (int ni = 0; ni < FN; ++ni)
      bfr[ni] = *(const bf16x8*)&Bs[(wn * (BN / 2) + ni * 16 + l15) * 32 + (l4 ^ sw) * 8];
#pragma unroll
    for (int mi = 0; mi < FM; ++mi)
#pragma unroll
      for (int ni = 0; ni < FN; ++ni)
        acc[mi][ni] = __builtin_amdgcn_mfma_f32_16x16x32_bf16(af[mi], bfr[ni], acc[mi][ni], 0, 0, 0);
    __syncthreads();  // t+1 loads drained; buf[t&1] reads done before overwrite
  }
}

// ---------------------------------------------------------------------------
// GEMM core (fp8 x fp8, BK=64, XOR-swizzled, 2-phase double-buffer):
// R12/R14-verified (VGPR 80-84 on k_gemm_s).
// ---------------------------------------------------------------------------
template <int BM, int BN>
__device__ __forceinline__ void gemm_core_fp8_db(
    const unsigned char* __restrict__ A, const unsigned char* __restrict__ Bt,
    int K, int m0, int n0, unsigned char* smem,
    f32x4 (&acc)[BM / 32][BN / 32])
{
  constexpr int FM = BM / 32, FN = BN / 32;
  constexpr int ASZ = (BM / 64) * 4096;   // A tile bytes (BM x 64)
  constexpr int BSZ = (BN / 64) * 4096;
  constexpr int BUF = ASZ + BSZ;
  const int tid = threadIdx.x;
  const int lane = tid & 63;
  const int wave = tid >> 6;
  const int wm = wave >> 1, wn = wave & 1;
  const int l15 = lane & 15, l4 = lane >> 4;
  const int sw = (l15 >> 1) & 3;
  const int h8 = (l4 & 1) * 8;      // 8B half within a 16B chunk
  const int nt = K >> 6;

  auto stage = [&](int b, int kt) {
    unsigned char* As_ = smem + b * BUF;
    unsigned char* Bs_ = As_ + ASZ;
#pragma unroll
    for (int i = 0; i < BM / 64; ++i) {
      int ci = i * 256 + tid;
      int row = ci >> 2, kc = ci & 3;
      int kcs = (kc ^ ((row >> 1) & 3)) * 16;  // swizzled 16B source chunk
      GLDS(A + (size_t)(m0 + row) * K + kt + kcs, As_ + i * 4096 + wave * 1024);
    }
#pragma unroll
    for (int i = 0; i < BN / 64; ++i) {
      int ci = i * 256 + tid;
      int row = ci >> 2, kc = ci & 3;
      int kcs = (kc ^ ((row >> 1) & 3)) * 16;
      GLDS(Bt + (size_t)(n0 + row) * K + kt + kcs, Bs_ + i * 4096 + wave * 1024);
    }
  };

  stage(0, 0);
  __syncthreads();                       // tile 0 valid
  for (int t = 0; t < nt; ++t) {
    if (t + 1 < nt) stage((t + 1) & 1, (t + 1) * 64);
    const unsigned char* As = smem + (t & 1) * BUF;
    const unsigned char* Bs = As + ASZ;
    long long af[FM][2], bfr[FN][2];
#pragma unroll
    for (int mi = 0; mi < FM; ++mi) {
      int row = wm * (BM / 2) + mi * 16 + l15;
#pragma unroll
      for (int j = 0; j < 2; ++j) {
        int G = j * 2 + (l4 >> 1);           // global 16B-chunk index
        af[mi][j] = *(const long long*)&As[row * 64 + ((G ^ sw) << 4) + h8];
      }
    }
#pragma unroll
    for (int ni = 0; ni < FN; ++ni) {
      int row = wn * (BN / 2) + ni * 16 + l15;
#pragma unroll
      for (int j = 0; j < 2; ++j) {
        int G = j * 2 + (l4 >> 1);
        bfr[ni][j] = *(const long long*)&Bs[row * 64 + ((G ^ sw) << 4) + h8];
      }
    }
#pragma unroll
    for (int mi = 0; mi < FM; ++mi)
#pragma unroll
      for (int ni = 0; ni < FN; ++ni) {
        f32x4 c = acc[mi][ni];
        c = __builtin_amdgcn_mfma_f32_16x16x32_fp8_fp8(af[mi][0], bfr[ni][0], c, 0, 0, 0);
        c = __builtin_amdgcn_mfma_f32_16x16x32_fp8_fp8(af[mi][1], bfr[ni][1], c, 0, 0, 0);
        acc[mi][ni] = c;
      }
    __syncthreads();  // t+1 loads drained; buf[t&1] reads done before overwrite
  }
}

// ---------------------------------------------------------------------------
// GEMM core (MX fp8, 32x32x64, scale=1.0, 2-phase double-buffer): PV only.
// A-operand: lane l holds row (l&31), k-bytes [ (l>>5)*32 , +32 ).
// C/D (m74/m101): col = lane&31, row = (r&3)+8*(r>>2)+4*(l>>5).
// ---------------------------------------------------------------------------
template <int BM, int BN>
__device__ __forceinline__ void gemm_core_mx32_db(
    const unsigned char* __restrict__ A, const unsigned char* __restrict__ Bt,
    int K, int m0, int n0, unsigned char* smem,
    f32x16 (&acc)[BM / 64][BN / 64])
{
  constexpr int FM = BM / 64, FN = BN / 64;
  constexpr int ASZ = (BM / 64) * 4096;
  constexpr int BSZ = (BN / 64) * 4096;
  constexpr int BUF = ASZ + BSZ;
  const int tid = threadIdx.x;
  const int lane = tid & 63;
  const int wave = tid >> 6;
  const int wm = wave >> 1, wn = wave & 1;
  const int l31 = lane & 31, h = lane >> 5;   // h: k-block of 32 bytes
  const int nt = K >> 6;

  auto stage = [&](int b, int kt) {
    unsigned char* As_ = smem + b * BUF;
    unsigned char* Bs_ = As_ + ASZ;
#pragma unroll
    for (int i = 0; i < BM / 64; ++i) {
      int ci = i * 256 + tid;
      int row = ci >> 2, kc = ci & 3;
      int kcs = (kc ^ ((row >> 1) & 3)) * 16;
      GLDS(A + (size_t)(m0 + row) * K + kt + kcs, As_ + i * 4096 + wave * 1024);
    }
#pragma unroll
    for (int i = 0; i < BN / 64; ++i) {
      int ci = i * 256 + tid;
      int row = ci >> 2, kc = ci & 3;
      int kcs = (kc ^ ((row >> 1) & 3)) * 16;
      GLDS(Bt + (size_t)(n0 + row) * K + kt + kcs, Bs_ + i * 4096 + wave * 1024);
    }
  };

  stage(0, 0);
  __syncthreads();
  for (int t = 0; t < nt; ++t) {
    if (t + 1 < nt) stage((t + 1) & 1, (t + 1) * 64);
    const unsigned char* As = smem + (t & 1) * BUF;
    const unsigned char* Bs = As + ASZ;
    i32x8 af[FM], bfr[FN];
#pragma unroll
    for (int mi = 0; mi < FM; ++mi) {
      int row = wm * (BM / 2) + mi * 32 + l31;
      int s = (row >> 1) & 3;
      int c0 = (2 * h) ^ s, c1 = (2 * h + 1) ^ s;   // two 16B chunks = 32B of k
      uint4 u0 = *(const uint4*)&As[row * 64 + c0 * 16];
      uint4 u1 = *(const uint4*)&As[row * 64 + c1 * 16];
      af[mi][0] = (int)u0.x; af[mi][1] = (int)u0.y; af[mi][2] = (int)u0.z; af[mi][3] = (int)u0.w;
      af[mi][4] = (int)u1.x; af[mi][5] = (int)u1.y; af[mi][6] = (int)u1.z; af[mi][7] = (int)u1.w;
    }
#pragma unroll
    for (int ni = 0; ni < FN; ++ni) {
      int row = wn * (BN / 2) + ni * 32 + l31;
      int s = (row >> 1) & 3;
      int c0 = (2 * h) ^ s, c1 = (2 * h + 1) ^ s;
      uint4 u0 = *(const uint4*)&Bs[row * 64 + c0 * 16];
      uint4 u1 = *(const uint4*)&Bs[row * 64 + c1 * 16];
      bfr[ni][0] = (int)u0.x; bfr[ni][1] = (int)u0.y; bfr[ni][2] = (int)u0.z; bfr[ni][3] = (int)u0.w;
      bfr[ni][4] = (int)u1.x; bfr[ni][5] = (int)u1.y; bfr[ni][6] = (int)u1.z; bfr[ni][7] = (int)u1.w;
    }
#pragma unroll
    for (int mi = 0; mi < FM; ++mi)
#pragma unroll
      for (int ni = 0; ni < FN; ++ni)
        acc[mi][ni] = __builtin_amdgcn_mfma_scale_f32_32x32x64_f8f6f4(
            af[mi], bfr[ni], acc[mi][ni],
            0, 0,                       // cbsz/blgp = fp8 e4m3
            0, 0x7f7f7f7f,              // scale_a: e8m0 = 1.0
            0, 0x7f7f7f7f);             // scale_b: e8m0 = 1.0
    __syncthreads();
  }
}

// fp8 16x16 C/D layout (measured m89/m91): col = lane&15, row = (lane>>4)*4 + reg.

// ---------------------------------------------------------------------------
// QKV GEMM: X[16384][512] @ Wqkv^T.  All outputs staged in LDS and written
// as coalesced 16B chunks: q8/k8 as [token][c] rows, v transposed to
// vt8[b][c][n] rows.  Bias folded into the staging conversion.  (R15-verified)
// ---------------------------------------------------------------------------
__global__ __launch_bounds__(256) void k_gemm_qkv(
    const __bf16* __restrict__ X, const __bf16* __restrict__ Wt,
    const float* __restrict__ bias, unsigned char* __restrict__ q8,
    unsigned char* __restrict__ k8, unsigned char* __restrict__ vt8)
{
  __shared__ __align__(16) __bf16 smem[2 * (128 * 32 + 128 * 32)];  // 32 KB dbuf
  f32x4 acc[4][4];
#pragma unroll
  for (int i = 0; i < 4; ++i)
#pragma unroll
    for (int j = 0; j < 4; ++j)
#pragma unroll
      for (int r = 0; r < 4; ++r) acc[i][j][r] = 0.f;
  const int m0 = blockIdx.x * 128, n0 = blockIdx.y * 128;
  gemm_core_db<128, 128>(X, Wt, 512, m0, n0, smem, acc);

  const int lane = threadIdx.x & 63, wave = threadIdx.x >> 6;
  const int wm = wave >> 1, wn = wave & 1, l15 = lane & 15, l4 = lane >> 4;

  // Stage the 128x128 fp8 patch in LDS (stride 144), then store coalesced.
  unsigned char* t8 = (unsigned char*)smem;  // 128*144 = 18432 B <= 32768
  if (blockIdx.y < 8) {
    // q or k: patch[token_local][c_local], no transpose
#pragma unroll
    for (int mi = 0; mi < 4; ++mi)
#pragma unroll
      for (int ni = 0; ni < 4; ++ni) {
        int lcol = wn * 64 + ni * 16 + l15;
        float bb = bias[n0 + lcol];
#pragma unroll
        for (int r = 0; r < 4; ++r) {
          int lrow = wm * 64 + mi * 16 + l4 * 4 + r;
          t8[lrow * 144 + lcol] = f2fp8(acc[mi][ni][r] + bb);
        }
      }
    __syncthreads();
    unsigned char* dst = (blockIdx.y < 4) ? q8 : k8;
    const int c0 = (blockIdx.y < 4) ? n0 : n0 - 512;
#pragma unroll
    for (int j = 0; j < 4; ++j) {
      int idx = j * 256 + threadIdx.x;
      int crow = idx >> 3, ccol = (idx & 7) * 16;
      uint4 v = *(const uint4*)&t8[crow * 144 + ccol];
      *(uint4*)&dst[(size_t)(m0 + crow) * 512 + c0 + ccol] = v;
    }
  } else {
    // v: patch transposed to [c_local][token_local]
#pragma unroll
    for (int mi = 0; mi < 4; ++mi)
#pragma unroll
      for (int ni = 0; ni < 4; ++ni) {
        int c_l = wn * 64 + ni * 16 + l15;
        float bb = bias[n0 + c_l];
#pragma unroll
        for (int r = 0; r < 4; ++r) {
          int n_l = wm * 64 + mi * 16 + l4 * 4 + r;
          t8[c_l * 144 + n_l] = f2fp8(acc[mi][ni][r] + bb);
        }
      }
    __syncthreads();
    const int b = m0 >> 12, nst = m0 & 4095;
    const int c0 = n0 - 1024;
#pragma unroll
    for (int j = 0; j < 4; ++j) {
      int idx = j * 256 + threadIdx.x;
      int crow = idx >> 3, ccol = (idx & 7) * 16;
      uint4 v = *(const uint4*)&t8[crow * 144 + ccol];
      *(uint4*)&vt8[((size_t)b * 512 + c0 + crow) * 4096 + nst + ccol] = v;
    }
  }
}

// ---------------------------------------------------------------------------
// Scores GEMM (fp8 x fp8, BK=64, 2-phase dbuf) + max-free softmax numerator,
// batched over z: P[b][n][m] = exp(q.k) stored fp8 e4m3; lsum fp32 row sums.
// Epilogue: exp+rowsum in regs, ONE-pass staging into 128x144 LDS tile,
// 16B-coalesced stores.  (R15-verified: 81.5us, VGPR 80.)
// ---------------------------------------------------------------------------
__global__ __launch_bounds__(256) void k_gemm_s(
    const unsigned char* __restrict__ qall, const unsigned char* __restrict__ kall,
    unsigned char* __restrict__ S8all, float* __restrict__ lsum)
{
  __shared__ __align__(16) unsigned char smem[32768];  // 2 x (8KB As + 8KB Bs)
  f32x4 acc[4][4];
#pragma unroll
  for (int i = 0; i < 4; ++i)
#pragma unroll
    for (int j = 0; j < 4; ++j)
#pragma unroll
      for (int r = 0; r < 4; ++r) acc[i][j][r] = 0.f;

  // supertile swizzle: 1024 blocks/batch -> 16 groups of 64 (8x8)
  const int b = blockIdx.z;
  const int flat = blockIdx.x + (blockIdx.y << 5);
  const int gx = flat & 7, gy = (flat >> 3) & 7, grp = flat >> 6;
  const int bx = (grp & 3) * 8 + gx, by = (grp >> 2) * 8 + gy;
  const int m0 = bx * 128, n0 = by * 128;

  const unsigned char* q = qall + (size_t)b * 4096 * 512;
  const unsigned char* k = kall + (size_t)b * 4096 * 512;
  unsigned char* S8 = S8all + (size_t)b * 4096 * 4096;
  gemm_core_fp8_db<128, 128>(q, k, 512, m0, n0, smem, acc);

  const int lane = threadIdx.x & 63, wave = threadIdx.x >> 6;
  const int wm = wave >> 1, wn = wave & 1, l15 = lane & 15, l4 = lane >> 4;

  // exp in place + fp32 row-sum atomics (pre-fp8-rounding; unbiased)
#pragma unroll
  for (int mi = 0; mi < 4; ++mi) {
    float rsum[4] = {0.f, 0.f, 0.f, 0.f};
#pragma unroll
    for (int ni = 0; ni < 4; ++ni)
#pragma unroll
      for (int r = 0; r < 4; ++r) {
        float p = __expf(acc[mi][ni][r]);
        acc[mi][ni][r] = p;
        rsum[r] += p;
      }
#pragma unroll
    for (int r = 0; r < 4; ++r) {
#pragma unroll
      for (int off = 1; off < 16; off <<= 1) rsum[r] += __shfl_xor(rsum[r], off, 64);
      if (l15 == 0) {
        int grow = m0 + wm * 64 + mi * 16 + l4 * 4 + r;
        atomicAdd(&lsum[b * 4096 + grow], rsum[r]);
      }
    }
  }

  // One-pass staging: all waves convert into t8[128][144], then store.
  unsigned char* t8 = smem;  // 128*144 = 18432 B <= 32768
#pragma unroll
  for (int mi = 0; mi < 4; ++mi)
#pragma unroll
    for (int ni = 0; ni < 4; ++ni) {
      int lcol = wn * 64 + ni * 16 + l15;
#pragma unroll
      for (int r = 0; r < 4; ++r) {
        int lrow = wm * 64 + mi * 16 + l4 * 4 + r;
        t8[lrow * 144 + lcol] = f2fp8(acc[mi][ni][r]);
      }
    }
  __syncthreads();
  // store 128 rows x 128 B: 1024 chunks of 16B, 4 per thread
#pragma unroll
  for (int j = 0; j < 4; ++j) {
    int idx = j * 256 + threadIdx.x;
    int crow = idx >> 3, ccol = (idx & 7) * 16;
    uint4 v = *(const uint4*)&t8[crow * 144 + ccol];
    *(uint4*)&S8[(size_t)(m0 + crow) * 4096 + n0 + ccol] = v;
  }
}

// ---------------------------------------------------------------------------
// PV GEMM (MX fp8 32x32x64, BK=64, 2-phase dbuf, 128x128), batched over z:
// O[b,n,c] = (sum_m P[b,n,m] * vt[b,c,m]) / l[b,n].  (R15-verified config.)
// ---------------------------------------------------------------------------
__global__ __launch_bounds__(256) void k_gemm_pv(
    const unsigned char* __restrict__ S8all, const unsigned char* __restrict__ vt8all,
    const float* __restrict__ lsum, __bf16* __restrict__ attn)
{
  __shared__ __align__(16) unsigned char smem[32768];  // 2 x (8KB As + 8KB Bs)
  f32x16 acc[2][2];
#pragma unroll
  for (int i = 0; i < 2; ++i)
#pragma unroll
    for (int j = 0; j < 2; ++j)
#pragma unroll
      for (int r = 0; r < 16; ++r) acc[i][j][r] = 0.f;
  const int b = blockIdx.z;
  const unsigned char* P = S8all + (size_t)b * 4096 * 4096;
  const unsigned char* V = vt8all + (size_t)b * 512 * 4096;
  __bf16* O = attn + (size_t)b * 4096 * 512;
  const int m0 = blockIdx.x * 128, n0 = blockIdx.y * 128;
  gemm_core_mx32_db<128, 128>(P, V, 4096, m0, n0, smem, acc);

  const int lane = threadIdx.x & 63, wave = threadIdx.x >> 6;
  const int wm = wave >> 1, wn = wave & 1, l31 = lane & 31, h = lane >> 5;
#pragma unroll
  for (int mi = 0; mi < 2; ++mi)
#pragma unroll
    for (int ni = 0; ni < 2; ++ni) {
      int gcol = n0 + wn * 64 + ni * 32 + l31;
#pragma unroll
      for (int r = 0; r < 16; ++r) {
        int grow = m0 + wm * 64 + mi * 32 + (r & 3) + 8 * (r >> 2) + 4 * h;
        float inv = 1.f / lsum[b * 4096 + grow];
        O[(size_t)grow * 512 + gcol] = (__bf16)(acc[mi][ni][r] * inv);
      }
    }
}

// ---------------------------------------------------------------------------
// Output projection + bias + residual, fp32 store to d_out.
// ---------------------------------------------------------------------------
__global__ __launch_bounds__(256) void k_gemm_out(
    const __bf16* __restrict__ A, const __bf16* __restrict__ Wot,
    const float* __restrict__ bo, const float* __restrict__ resid, float* __restrict__ out)
{
  __shared__ __align__(16) __bf16 smem[2 * (128 * 32 + 128 * 32)];  // 32 KB dbuf
  f32x4 acc[4][4];
#pragma unroll
  for (int i = 0; i < 4; ++i)
#pragma unroll
    for (int j = 0; j < 4; ++j)
#pragma unroll
      for (int r = 0; r < 4; ++r) acc[i][j][r] = 0.f;
  const int m0 = blockIdx.x * 128, n0 = blockIdx.y * 128;
  gemm_core_db<128, 128>(A, Wot, 512, m0, n0, smem, acc);

  const int lane = threadIdx.x & 63, wave = threadIdx.x >> 6;
  const int wm = wave >> 1, wn = wave & 1, l15 = lane & 15, l4 = lane >> 4;
#pragma unroll
  for (int mi = 0; mi < 4; ++mi)
#pragma unroll
    for (int ni = 0; ni < 4; ++ni) {
      int gcol = n0 + wn * 64 + ni * 16 + l15;
      float bb = bo[gcol];
#pragma unroll
      for (int r = 0; r < 4; ++r) {
        int grow = m0 + wm * 64 + mi * 16 + l4 * 4 + r;
        size_t idx = (size_t)grow * 512 + gcol;
        out[idx] = acc[mi][ni][r] + bb + resid[idx];
      }
    }
}

// ---------------------------------------------------------------------------
extern "C" void kernel_launch(void* const* d_in, const int* in_sizes, int n_in,
                              void* d_out, int out_size, void* d_ws, size_t ws_size,
                              hipStream_t stream)
{
  const float* x     = (const float*)d_in[0];
  const float* gamma = (const float*)d_in[1];
  const float* beta  = (const float*)d_in[2];
  const float* wq    = (const float*)d_in[3];
  const float* bq    = (const float*)d_in[4];
  const float* wk    = (const float*)d_in[5];
  const float* bk    = (const float*)d_in[6];
  const float* wv    = (const float*)d_in[7];
  const float* bv    = (const float*)d_in[8];
  const float* wo    = (const float*)d_in[9];
  const float* bo    = (const float*)d_in[10];
  float* out = (float*)d_out;

  char* ws = (char*)d_ws;
  size_t off = 0;
  auto alloc = [&](size_t bytes) -> char* {
    char* p = ws + off;
    off += (bytes + 255) & ~(size_t)255;
    return p;
  };
  float*  gns     = (float*)alloc(128 * 4);
  float*  gnss    = (float*)alloc(128 * 4);
  __bf16* x16     = (__bf16*)alloc(16384ull * 512 * 2);   // 16 MB
  __bf16* wqkvt   = (__bf16*)alloc(1536ull * 512 * 2);    // 1.5 MB
  float*  biasqkv = (float*)alloc(1536 * 4);
  __bf16* wot     = (__bf16*)alloc(512ull * 512 * 2);     // 0.5 MB
  float*  lsum    = (float*)alloc(16384ull * 4);          // 64 KB row sums
  unsigned char* q8  = (unsigned char*)alloc(16384ull * 512);     // 8 MB fp8 Q
  unsigned char* k8  = (unsigned char*)alloc(16384ull * 512);     // 8 MB fp8 K
  unsigned char* vt8 = (unsigned char*)alloc(16384ull * 512);     // 8 MB fp8 V^T
  __bf16* attn    = (__bf16*)alloc(16384ull * 512 * 2);   // 16 MB
  unsigned char* S8 = (unsigned char*)alloc(4ull * 4096 * 4096);  // 64 MB fp8 exp(scores)
  // total ~122 MB

  k_prep<<<dim3(4167), dim3(256), 0, stream>>>(wq, bq, wk, bk, wv, bv, wo,
                                               wqkvt, biasqkv, wot, lsum, gns, gnss);
  k_gnstats<<<dim3(1024), dim3(256), 0, stream>>>(x, gns, gnss);
  k_norm<<<dim3(8192), dim3(256), 0, stream>>>(x, gns, gnss, gamma, beta, x16);
  k_gemm_qkv<<<dim3(128, 12), dim3(256), 0, stream>>>(x16, wqkvt, biasqkv, q8, k8, vt8);
  k_gemm_s<<<dim3(32, 32, 4), dim3(256), 0, stream>>>(q8, k8, S8, lsum);
  k_gemm_pv<<<dim3(32, 4, 4), dim3(256), 0, stream>>>(S8, vt8, lsum, attn);
  k_gemm_out<<<dim3(128, 4), dim3(256), 0, stream>>>(attn, wot, bo, x, out);
}

// Round 12
// 297.397 us; speedup vs baseline: 1.0702x; 1.0001x over previous
//
#include <hip/hip_runtime.h>

// ---------------------------------------------------------------------------
// VAEAttention: GroupNorm(32) -> q,k,v 1x1 conv -> full spatial attention
// (N=4096 tokens, d=512) -> out proj -> +residual.   B=4, H=W=64, C=512.
// R18: PV gets a 3-buffer counted-vmcnt pipeline (T3/T4 minimal form):
// per tile {stage(t+2) -> s_waitcnt vmcnt(8) -> s_barrier -> ds_read+MFMA ->
// s_barrier}; loads stay in flight ACROSS barriers (no vmcnt(0) drain in the
// 64-deep K loop).  PV only (2 blocks/CU grid -> drains exposed there).
// Everything else identical to R17 (297.4us).
// ---------------------------------------------------------------------------

typedef __bf16 bf16x8 __attribute__((ext_vector_type(8)));
typedef __bf16 bf16x4 __attribute__((ext_vector_type(4)));
typedef float  f32x4  __attribute__((ext_vector_type(4)));
typedef float  f32x16 __attribute__((ext_vector_type(16)));
typedef int    i32x8  __attribute__((ext_vector_type(8)));

#define GLDS(gp, lp) __builtin_amdgcn_global_load_lds( \
    (const __attribute__((address_space(1))) void*)(gp), \
    (__attribute__((address_space(3))) void*)(lp), 16, 0, 0)

// fp32 -> fp8 e4m3 (OCP on gfx950), RNE via HW cvt. Low byte of packed pair.
__device__ __forceinline__ unsigned char f2fp8(float x) {
  int p = __builtin_amdgcn_cvt_pk_fp8_f32(x, 0.f, 0, false);
  return (unsigned char)(p & 0xff);
}

// ---------------------------------------------------------------------------
// GroupNorm partial stats: 1024 blocks = 8 chunks per (b,g).  Each block
// reduces 512 pixels x 16 channels = 32KB and atomicAdds (s, ss) into
// gns/gnss[128] (zeroed by k_prep, launched before this).
// ---------------------------------------------------------------------------
__global__ __launch_bounds__(256) void k_gnstats(
    const float* __restrict__ x, float* __restrict__ gns, float* __restrict__ gnss)
{
  const int blk = blockIdx.x;           // 0..1023
  const int bg = blk >> 3, chunk = blk & 7;
  const int b = bg >> 5, g = bg & 31;
  const float* base = x + (size_t)b * 2097152 + g * 16;
  float s = 0.f, ss = 0.f;
#pragma unroll
  for (int it = 0; it < 2; ++it) {
    int p = chunk * 512 + it * 256 + threadIdx.x;
    const float4* rp = (const float4*)(base + (size_t)p * 512);
#pragma unroll
    for (int j = 0; j < 4; ++j) {
      float4 t = rp[j];
      s  += t.x + t.y + t.z + t.w;
      ss += t.x * t.x + t.y * t.y + t.z * t.z + t.w * t.w;
    }
  }
  for (int off = 32; off; off >>= 1) { s += __shfl_xor(s, off, 64); ss += __shfl_xor(ss, off, 64); }
  __shared__ float rs[4], rss[4];
  if ((threadIdx.x & 63) == 0) { rs[threadIdx.x >> 6] = s; rss[threadIdx.x >> 6] = ss; }
  __syncthreads();
  if (threadIdx.x == 0) {
    atomicAdd(&gns[bg],  rs[0] + rs[1] + rs[2] + rs[3]);
    atomicAdd(&gnss[bg], rss[0] + rss[1] + rss[2] + rss[3]);
  }
}

// ---------------------------------------------------------------------------
// Normalize + affine + cast to bf16; finalizes mean/rstd from (s, ss).
// ---------------------------------------------------------------------------
__global__ __launch_bounds__(256) void k_norm(
    const float* __restrict__ x, const float* __restrict__ gns,
    const float* __restrict__ gnss, const float* __restrict__ gamma,
    const float* __restrict__ beta, __bf16* __restrict__ x16)
{
  size_t i4 = (size_t)blockIdx.x * 256 + threadIdx.x;  // 0..2097151
  size_t i = i4 * 4;
  int c = (int)(i & 511);
  int bg = (int)(i >> 21) * 32 + (c >> 4);
  float s = gns[bg], ss = gnss[bg];
  float m = s * (1.f / 65536.f);
  float var = ss * (1.f / 65536.f) - m * m;
  float r = rsqrtf(var + 1e-6f);
  float4 xv = *(const float4*)(x + i);
  float4 gv = *(const float4*)(gamma + c);
  float4 bv = *(const float4*)(beta + c);
  bf16x4 o;
  o[0] = (__bf16)((xv.x - m) * r * gv.x + bv.x);
  o[1] = (__bf16)((xv.y - m) * r * gv.y + bv.y);
  o[2] = (__bf16)((xv.z - m) * r * gv.z + bv.z);
  o[3] = (__bf16)((xv.w - m) * r * gv.w + bv.w);
  *(bf16x4*)(x16 + i) = o;
}

// ---------------------------------------------------------------------------
// Weight prep: Bt layouts (row = output dim, contiguous K).
// wqkvt[1536][512] (wq scaled by 1/sqrt(512)), biasqkv[1536], wot[512][512].
// Also zeroes lsum[16384] and the GN stat buffers gns/gnss[128] (tail).
// ---------------------------------------------------------------------------
__global__ __launch_bounds__(256) void k_prep(
    const float* __restrict__ wq, const float* __restrict__ bq,
    const float* __restrict__ wk, const float* __restrict__ bk,
    const float* __restrict__ wv, const float* __restrict__ bv,
    const float* __restrict__ wo,
    __bf16* __restrict__ wqkvt, float* __restrict__ biasqkv, __bf16* __restrict__ wot,
    float* __restrict__ lsum, float* __restrict__ gns, float* __restrict__ gnss)
{
  const float sc = 0.04419417382415922f;  // 1/sqrt(512)
  int idx = blockIdx.x * 256 + threadIdx.x;
  if (idx < 786432) {
    int d = idx >> 9, c = idx & 511;
    float v;
    if (d < 512)       v = wq[c * 512 + d] * sc;
    else if (d < 1024) v = wk[c * 512 + d - 512];
    else               v = wv[c * 512 + d - 1024];
    wqkvt[idx] = (__bf16)v;
  } else if (idx < 786432 + 262144) {
    int j = idx - 786432;
    int d = j >> 9, c = j & 511;
    wot[j] = (__bf16)wo[c * 512 + d];
  } else if (idx < 786432 + 262144 + 1536) {
    int d = idx - 786432 - 262144;
    float v = (d < 512) ? bq[d] * sc : (d < 1024 ? bk[d - 512] : bv[d - 1024]);
    biasqkv[d] = v;
  } else if (idx < 786432 + 262144 + 1536 + 16384) {
    lsum[idx - 786432 - 262144 - 1536] = 0.f;
  } else if (idx < 786432 + 262144 + 1536 + 16384 + 256) {
    int j = idx - 786432 - 262144 - 1536 - 16384;
    if (j < 128) gns[j] = 0.f; else gnss[j - 128] = 0.f;
  }
}

// ---------------------------------------------------------------------------
// GEMM core (bf16, XOR-swizzled LDS, 2-phase double-buffer):
// prologue stages tile 0; per tile: STAGE(t+1) -> ds_read+MFMA(t) -> ONE
// barrier (R14-verified).
// ---------------------------------------------------------------------------
template <int BM, int BN>
__device__ __forceinline__ void gemm_core_db(
    const __bf16* __restrict__ A, const __bf16* __restrict__ Bt, int K,
    int m0, int n0, __bf16* smem, f32x4 (&acc)[BM / 32][BN / 32])
{
  constexpr int FM = BM / 32, FN = BN / 32;
  constexpr int ASZ = BM * 32;          // elements per A tile (BM x 32)
  constexpr int BSZ = BN * 32;
  constexpr int BUF = ASZ + BSZ;
  const int tid = threadIdx.x;
  const int lane = tid & 63;
  const int wave = tid >> 6;
  const int wm = wave >> 1, wn = wave & 1;
  const int l15 = lane & 15, l4 = lane >> 4;
  const int sw = (l15 >> 1) & 3;            // read-side chunk swizzle
  const int nt = K >> 5;

  auto stage = [&](int b, int kt) {
    __bf16* As_ = smem + b * BUF;
    __bf16* Bs_ = As_ + ASZ;
#pragma unroll
    for (int i = 0; i < BM / 64; ++i) {
      int ci = i * 256 + tid;
      int row = ci >> 2, kc = ci & 3;
      int kcs = kc ^ ((row >> 1) & 3);       // swizzled source chunk
      GLDS(A + (size_t)(m0 + row) * K + kt + kcs * 8, As_ + i * 2048 + wave * 512);
    }
#pragma unroll
    for (int i = 0; i < BN / 64; ++i) {
      int ci = i * 256 + tid;
      int row = ci >> 2, kc = ci & 3;
      int kcs = kc ^ ((row >> 1) & 3);
      GLDS(Bt + (size_t)(n0 + row) * K + kt + kcs * 8, Bs_ + i * 2048 + wave * 512);
    }
  };

  stage(0, 0);
  __syncthreads();                       // tile 0 valid
  for (int t = 0; t < nt; ++t) {
    if (t + 1 < nt) stage((t + 1) & 1, (t + 1) * 32);
    const __bf16* As = smem + (t & 1) * BUF;
    const __bf16* Bs = As + ASZ;
    bf16x8 af[FM], bfr[FN];
#pragma unroll
    for (int mi = 0; mi < FM; ++mi)
      af[mi] = *(const bf16x8*)&As[(wm * (BM / 2) + mi * 16 + l15) * 32 + (l4 ^ sw) * 8];
#pragma unroll
    for (int ni = 0; ni < FN; ++ni)
      bfr[ni] = *(const bf16x8*)&Bs[(wn * (BN / 2) + ni * 16 + l15) * 32 + (l4 ^ sw) * 8];
#pragma unroll
    for (int mi = 0; mi < FM; ++mi)
#pragma unroll
      for (int ni = 0; ni < FN; ++ni)
        acc[mi][ni] = __builtin_amdgcn_mfma_f32_16x16x32_bf16(af[mi], bfr[ni], acc[mi][ni], 0, 0, 0);
    __syncthreads();  // t+1 loads drained; buf[t&1] reads done before overwrite
  }
}

// ---------------------------------------------------------------------------
// GEMM core (fp8 x fp8, BK=64, XOR-swizzled, 2-phase double-buffer):
// R12/R14-verified (VGPR 80-84 on k_gemm_s).
// ---------------------------------------------------------------------------
template <int BM, int BN>
__device__ __forceinline__ void gemm_core_fp8_db(
    const unsigned char* __restrict__ A, const unsigned char* __restrict__ Bt,
    int K, int m0, int n0, unsigned char* smem,
    f32x4 (&acc)[BM / 32][BN / 32])
{
  constexpr int FM = BM / 32, FN = BN / 32;
  constexpr int ASZ = (BM / 64) * 4096;   // A tile bytes (BM x 64)
  constexpr int BSZ = (BN / 64) * 4096;
  constexpr int BUF = ASZ + BSZ;
  const int tid = threadIdx.x;
  const int lane = tid & 63;
  const int wave = tid >> 6;
  const int wm = wave >> 1, wn = wave & 1;
  const int l15 = lane & 15, l4 = lane >> 4;
  const int sw = (l15 >> 1) & 3;
  const int h8 = (l4 & 1) * 8;      // 8B half within a 16B chunk
  const int nt = K >> 6;

  auto stage = [&](int b, int kt) {
    unsigned char* As_ = smem + b * BUF;
    unsigned char* Bs_ = As_ + ASZ;
#pragma unroll
    for (int i = 0; i < BM / 64; ++i) {
      int ci = i * 256 + tid;
      int row = ci >> 2, kc = ci & 3;
      int kcs = (kc ^ ((row >> 1) & 3)) * 16;  // swizzled 16B source chunk
      GLDS(A + (size_t)(m0 + row) * K + kt + kcs, As_ + i * 4096 + wave * 1024);
    }
#pragma unroll
    for (int i = 0; i < BN / 64; ++i) {
      int ci = i * 256 + tid;
      int row = ci >> 2, kc = ci & 3;
      int kcs = (kc ^ ((row >> 1) & 3)) * 16;
      GLDS(Bt + (size_t)(n0 + row) * K + kt + kcs, Bs_ + i * 4096 + wave * 1024);
    }
  };

  stage(0, 0);
  __syncthreads();                       // tile 0 valid
  for (int t = 0; t < nt; ++t) {
    if (t + 1 < nt) stage((t + 1) & 1, (t + 1) * 64);
    const unsigned char* As = smem + (t & 1) * BUF;
    const unsigned char* Bs = As + ASZ;
    long long af[FM][2], bfr[FN][2];
#pragma unroll
    for (int mi = 0; mi < FM; ++mi) {
      int row = wm * (BM / 2) + mi * 16 + l15;
#pragma unroll
      for (int j = 0; j < 2; ++j) {
        int G = j * 2 + (l4 >> 1);           // global 16B-chunk index
        af[mi][j] = *(const long long*)&As[row * 64 + ((G ^ sw) << 4) + h8];
      }
    }
#pragma unroll
    for (int ni = 0; ni < FN; ++ni) {
      int row = wn * (BN / 2) + ni * 16 + l15;
#pragma unroll
      for (int j = 0; j < 2; ++j) {
        int G = j * 2 + (l4 >> 1);
        bfr[ni][j] = *(const long long*)&Bs[row * 64 + ((G ^ sw) << 4) + h8];
      }
    }
#pragma unroll
    for (int mi = 0; mi < FM; ++mi)
#pragma unroll
      for (int ni = 0; ni < FN; ++ni) {
        f32x4 c = acc[mi][ni];
        c = __builtin_amdgcn_mfma_f32_16x16x32_fp8_fp8(af[mi][0], bfr[ni][0], c, 0, 0, 0);
        c = __builtin_amdgcn_mfma_f32_16x16x32_fp8_fp8(af[mi][1], bfr[ni][1], c, 0, 0, 0);
        acc[mi][ni] = c;
      }
    __syncthreads();  // t+1 loads drained; buf[t&1] reads done before overwrite
  }
}

// ---------------------------------------------------------------------------
// GEMM core (MX fp8, 32x32x64, scale=1.0, 3-buffer COUNTED-VMCNT pipeline):
// per tile: stage(t+2) -> s_waitcnt vmcnt(8) -> s_barrier -> ds_read+MFMA ->
// s_barrier.  4 gload_lds per thread per stage; vmcnt(8) leaves stages
// t+1,t+2 in flight and drains t (FIFO).  Every wave drains its OWN t-loads
// before the barrier => after barrier all t-loads landed.  stage(t+2)
// overwrites the buffer read at t-1, protected by t-1's end barrier.
// sched_barrier(0) pins ds_reads/stages against motion across raw barriers.
// A-operand: lane l holds row (l&31), k-bytes [ (l>>5)*32 , +32 ).
// C/D (m74/m101): col = lane&31, row = (r&3)+8*(r>>2)+4*(l>>5).
// ---------------------------------------------------------------------------
template <int BM, int BN>
__device__ __forceinline__ void gemm_core_mx32_p3(
    const unsigned char* __restrict__ A, const unsigned char* __restrict__ Bt,
    int K, int m0, int n0, unsigned char* smem,
    f32x16 (&acc)[BM / 64][BN / 64])
{
  constexpr int FM = BM / 64, FN = BN / 64;
  constexpr int ASZ = (BM / 64) * 4096;
  constexpr int BSZ = (BN / 64) * 4096;
  constexpr int BUF = ASZ + BSZ;
  const int tid = threadIdx.x;
  const int lane = tid & 63;
  const int wave = tid >> 6;
  const int wm = wave >> 1, wn = wave & 1;
  const int l31 = lane & 31, h = lane >> 5;   // h: k-block of 32 bytes
  const int nt = K >> 6;

  auto stage = [&](int b, int t) {
    const int kt = t * 64;
    unsigned char* As_ = smem + b * BUF;
    unsigned char* Bs_ = As_ + ASZ;
#pragma unroll
    for (int i = 0; i < BM / 64; ++i) {
      int ci = i * 256 + tid;
      int row = ci >> 2, kc = ci & 3;
      int kcs = (kc ^ ((row >> 1) & 3)) * 16;
      GLDS(A + (size_t)(m0 + row) * K + kt + kcs, As_ + i * 4096 + wave * 1024);
    }
#pragma unroll
    for (int i = 0; i < BN / 64; ++i) {
      int ci = i * 256 + tid;
      int row = ci >> 2, kc = ci & 3;
      int kcs = (kc ^ ((row >> 1) & 3)) * 16;
      GLDS(Bt + (size_t)(n0 + row) * K + kt + kcs, Bs_ + i * 4096 + wave * 1024);
    }
  };

  stage(0, 0);
  stage(1, 1);
  int cb = 0, sb = 2;                    // compute buffer / stage buffer
  for (int t = 0; t < nt; ++t) {
    if (t + 2 < nt) stage(sb, t + 2);
    // Drain own stage-t loads; keep stages t+1 (and t+2 if issued) in flight.
    if (t + 2 < nt)      asm volatile("s_waitcnt vmcnt(8)" ::: "memory");
    else if (t + 1 < nt) asm volatile("s_waitcnt vmcnt(4)" ::: "memory");
    else                 asm volatile("s_waitcnt vmcnt(0)" ::: "memory");
    __builtin_amdgcn_s_barrier();        // all waves' t-loads landed
    __builtin_amdgcn_sched_barrier(0);
    const unsigned char* As = smem + cb * BUF;
    const unsigned char* Bs = As + ASZ;
    i32x8 af[FM], bfr[FN];
#pragma unroll
    for (int mi = 0; mi < FM; ++mi) {
      int row = wm * (BM / 2) + mi * 32 + l31;
      int s = (row >> 1) & 3;
      int c0 = (2 * h) ^ s, c1 = (2 * h + 1) ^ s;   // two 16B chunks = 32B of k
      uint4 u0 = *(const uint4*)&As[row * 64 + c0 * 16];
      uint4 u1 = *(const uint4*)&As[row * 64 + c1 * 16];
      af[mi][0] = (int)u0.x; af[mi][1] = (int)u0.y; af[mi][2] = (int)u0.z; af[mi][3] = (int)u0.w;
      af[mi][4] = (int)u1.x; af[mi][5] = (int)u1.y; af[mi][6] = (int)u1.z; af[mi][7] = (int)u1.w;
    }
#pragma unroll
    for (int ni = 0; ni < FN; ++ni) {
      int row = wn * (BN / 2) + ni * 32 + l31;
      int s = (row >> 1) & 3;
      int c0 = (2 * h) ^ s, c1 = (2 * h + 1) ^ s;
      uint4 u0 = *(const uint4*)&Bs[row * 64 + c0 * 16];
      uint4 u1 = *(const uint4*)&Bs[row * 64 + c1 * 16];
      bfr[ni][0] = (int)u0.x; bfr[ni][1] = (int)u0.y; bfr[ni][2] = (int)u0.z; bfr[ni][3] = (int)u0.w;
      bfr[ni][4] = (int)u1.x; bfr[ni][5] = (int)u1.y; bfr[ni][6] = (int)u1.z; bfr[ni][7] = (int)u1.w;
    }
#pragma unroll
    for (int mi = 0; mi < FM; ++mi)
#pragma unroll
      for (int ni = 0; ni < FN; ++ni)
        acc[mi][ni] = __builtin_amdgcn_mfma_scale_f32_32x32x64_f8f6f4(
            af[mi], bfr[ni], acc[mi][ni],
            0, 0,                       // cbsz/blgp = fp8 e4m3
            0, 0x7f7f7f7f,              // scale_a: e8m0 = 1.0
            0, 0x7f7f7f7f);             // scale_b: e8m0 = 1.0
    __builtin_amdgcn_sched_barrier(0);   // ds_reads complete before barrier
    __builtin_amdgcn_s_barrier();        // readers of buf cb done; cb is the
    __builtin_amdgcn_sched_barrier(0);   // buffer staged at iter t+1
    cb = (cb == 2) ? 0 : cb + 1;
    sb = (sb == 2) ? 0 : sb + 1;
  }
}

// fp8 16x16 C/D layout (measured m89/m91): col = lane&15, row = (lane>>4)*4 + reg.

// ---------------------------------------------------------------------------
// QKV GEMM: X[16384][512] @ Wqkv^T.  All outputs staged in LDS and written
// as coalesced 16B chunks: q8/k8 as [token][c] rows, v transposed to
// vt8[b][c][n] rows.  Bias folded into the staging conversion.  (R15-verified)
// ---------------------------------------------------------------------------
__global__ __launch_bounds__(256) void k_gemm_qkv(
    const __bf16* __restrict__ X, const __bf16* __restrict__ Wt,
    const float* __restrict__ bias, unsigned char* __restrict__ q8,
    unsigned char* __restrict__ k8, unsigned char* __restrict__ vt8)
{
  __shared__ __align__(16) __bf16 smem[2 * (128 * 32 + 128 * 32)];  // 32 KB dbuf
  f32x4 acc[4][4];
#pragma unroll
  for (int i = 0; i < 4; ++i)
#pragma unroll
    for (int j = 0; j < 4; ++j)
#pragma unroll
      for (int r = 0; r < 4; ++r) acc[i][j][r] = 0.f;
  const int m0 = blockIdx.x * 128, n0 = blockIdx.y * 128;
  gemm_core_db<128, 128>(X, Wt, 512, m0, n0, smem, acc);

  const int lane = threadIdx.x & 63, wave = threadIdx.x >> 6;
  const int wm = wave >> 1, wn = wave & 1, l15 = lane & 15, l4 = lane >> 4;

  // Stage the 128x128 fp8 patch in LDS (stride 144), then store coalesced.
  unsigned char* t8 = (unsigned char*)smem;  // 128*144 = 18432 B <= 32768
  if (blockIdx.y < 8) {
    // q or k: patch[token_local][c_local], no transpose
#pragma unroll
    for (int mi = 0; mi < 4; ++mi)
#pragma unroll
      for (int ni = 0; ni < 4; ++ni) {
        int lcol = wn * 64 + ni * 16 + l15;
        float bb = bias[n0 + lcol];
#pragma unroll
        for (int r = 0; r < 4; ++r) {
          int lrow = wm * 64 + mi * 16 + l4 * 4 + r;
          t8[lrow * 144 + lcol] = f2fp8(acc[mi][ni][r] + bb);
        }
      }
    __syncthreads();
    unsigned char* dst = (blockIdx.y < 4) ? q8 : k8;
    const int c0 = (blockIdx.y < 4) ? n0 : n0 - 512;
#pragma unroll
    for (int j = 0; j < 4; ++j) {
      int idx = j * 256 + threadIdx.x;
      int crow = idx >> 3, ccol = (idx & 7) * 16;
      uint4 v = *(const uint4*)&t8[crow * 144 + ccol];
      *(uint4*)&dst[(size_t)(m0 + crow) * 512 + c0 + ccol] = v;
    }
  } else {
    // v: patch transposed to [c_local][token_local]
#pragma unroll
    for (int mi = 0; mi < 4; ++mi)
#pragma unroll
      for (int ni = 0; ni < 4; ++ni) {
        int c_l = wn * 64 + ni * 16 + l15;
        float bb = bias[n0 + c_l];
#pragma unroll
        for (int r = 0; r < 4; ++r) {
          int n_l = wm * 64 + mi * 16 + l4 * 4 + r;
          t8[c_l * 144 + n_l] = f2fp8(acc[mi][ni][r] + bb);
        }
      }
    __syncthreads();
    const int b = m0 >> 12, nst = m0 & 4095;
    const int c0 = n0 - 1024;
#pragma unroll
    for (int j = 0; j < 4; ++j) {
      int idx = j * 256 + threadIdx.x;
      int crow = idx >> 3, ccol = (idx & 7) * 16;
      uint4 v = *(const uint4*)&t8[crow * 144 + ccol];
      *(uint4*)&vt8[((size_t)b * 512 + c0 + crow) * 4096 + nst + ccol] = v;
    }
  }
}

// ---------------------------------------------------------------------------
// Scores GEMM (fp8 x fp8, BK=64, 2-phase dbuf) + max-free softmax numerator,
// batched over z: P[b][n][m] = exp(q.k) stored fp8 e4m3; lsum fp32 row sums.
// Epilogue: exp+rowsum in regs, ONE-pass staging into 128x144 LDS tile,
// 16B-coalesced stores.  (R15-verified: 81.3us, VGPR 80.)
// ---------------------------------------------------------------------------
__global__ __launch_bounds__(256) void k_gemm_s(
    const unsigned char* __restrict__ qall, const unsigned char* __restrict__ kall,
    unsigned char* __restrict__ S8all, float* __restrict__ lsum)
{
  __shared__ __align__(16) unsigned char smem[32768];  // 2 x (8KB As + 8KB Bs)
  f32x4 acc[4][4];
#pragma unroll
  for (int i = 0; i < 4; ++i)
#pragma unroll
    for (int j = 0; j < 4; ++j)
#pragma unroll
      for (int r = 0; r < 4; ++r) acc[i][j][r] = 0.f;

  // supertile swizzle: 1024 blocks/batch -> 16 groups of 64 (8x8)
  const int b = blockIdx.z;
  const int flat = blockIdx.x + (blockIdx.y << 5);
  const int gx = flat & 7, gy = (flat >> 3) & 7, grp = flat >> 6;
  const int bx = (grp & 3) * 8 + gx, by = (grp >> 2) * 8 + gy;
  const int m0 = bx * 128, n0 = by * 128;

  const unsigned char* q = qall + (size_t)b * 4096 * 512;
  const unsigned char* k = kall + (size_t)b * 4096 * 512;
  unsigned char* S8 = S8all + (size_t)b * 4096 * 4096;
  gemm_core_fp8_db<128, 128>(q, k, 512, m0, n0, smem, acc);

  const int lane = threadIdx.x & 63, wave = threadIdx.x >> 6;
  const int wm = wave >> 1, wn = wave & 1, l15 = lane & 15, l4 = lane >> 4;

  // exp in place + fp32 row-sum atomics (pre-fp8-rounding; unbiased)
#pragma unroll
  for (int mi = 0; mi < 4; ++mi) {
    float rsum[4] = {0.f, 0.f, 0.f, 0.f};
#pragma unroll
    for (int ni = 0; ni < 4; ++ni)
#pragma unroll
      for (int r = 0; r < 4; ++r) {
        float p = __expf(acc[mi][ni][r]);
        acc[mi][ni][r] = p;
        rsum[r] += p;
      }
#pragma unroll
    for (int r = 0; r < 4; ++r) {
#pragma unroll
      for (int off = 1; off < 16; off <<= 1) rsum[r] += __shfl_xor(rsum[r], off, 64);
      if (l15 == 0) {
        int grow = m0 + wm * 64 + mi * 16 + l4 * 4 + r;
        atomicAdd(&lsum[b * 4096 + grow], rsum[r]);
      }
    }
  }

  // One-pass staging: all waves convert into t8[128][144], then store.
  unsigned char* t8 = smem;  // 128*144 = 18432 B <= 32768
#pragma unroll
  for (int mi = 0; mi < 4; ++mi)
#pragma unroll
    for (int ni = 0; ni < 4; ++ni) {
      int lcol = wn * 64 + ni * 16 + l15;
#pragma unroll
      for (int r = 0; r < 4; ++r) {
        int lrow = wm * 64 + mi * 16 + l4 * 4 + r;
        t8[lrow * 144 + lcol] = f2fp8(acc[mi][ni][r]);
      }
    }
  __syncthreads();
  // store 128 rows x 128 B: 1024 chunks of 16B, 4 per thread
#pragma unroll
  for (int j = 0; j < 4; ++j) {
    int idx = j * 256 + threadIdx.x;
    int crow = idx >> 3, ccol = (idx & 7) * 16;
    uint4 v = *(const uint4*)&t8[crow * 144 + ccol];
    *(uint4*)&S8[(size_t)(m0 + crow) * 4096 + n0 + ccol] = v;
  }
}

// ---------------------------------------------------------------------------
// PV GEMM (MX fp8 32x32x64, BK=64, 3-buffer counted-vmcnt pipeline, 128x128),
// batched over z: O[b,n,c] = (sum_m P[b,n,m] * vt[b,c,m]) / l[b,n].
// ---------------------------------------------------------------------------
__global__ __launch_bounds__(256) void k_gemm_pv(
    const unsigned char* __restrict__ S8all, const unsigned char* __restrict__ vt8all,
    const float* __restrict__ lsum, __bf16* __restrict__ attn)
{
  __shared__ __align__(16) unsigned char smem[49152];  // 3 x (8KB As + 8KB Bs)
  f32x16 acc[2][2];
#pragma unroll
  for (int i = 0; i < 2; ++i)
#pragma unroll
    for (int j = 0; j < 2; ++j)
#pragma unroll
      for (int r = 0; r < 16; ++r) acc[i][j][r] = 0.f;
  const int b = blockIdx.z;
  const unsigned char* P = S8all + (size_t)b * 4096 * 4096;
  const unsigned char* V = vt8all + (size_t)b * 512 * 4096;
  __bf16* O = attn + (size_t)b * 4096 * 512;
  const int m0 = blockIdx.x * 128, n0 = blockIdx.y * 128;
  gemm_core_mx32_p3<128, 128>(P, V, 4096, m0, n0, smem, acc);

  const int lane = threadIdx.x & 63, wave = threadIdx.x >> 6;
  const int wm = wave >> 1, wn = wave & 1, l31 = lane & 31, h = lane >> 5;
#pragma unroll
  for (int mi = 0; mi < 2; ++mi)
#pragma unroll
    for (int ni = 0; ni < 2; ++ni) {
      int gcol = n0 + wn * 64 + ni * 32 + l31;
#pragma unroll
      for (int r = 0; r < 16; ++r) {
        int grow = m0 + wm * 64 + mi * 32 + (r & 3) + 8 * (r >> 2) + 4 * h;
        float inv = 1.f / lsum[b * 4096 + grow];
        O[(size_t)grow * 512 + gcol] = (__bf16)(acc[mi][ni][r] * inv);
      }
    }
}

// ---------------------------------------------------------------------------
// Output projection + bias + residual, fp32 store to d_out.
// ---------------------------------------------------------------------------
__global__ __launch_bounds__(256) void k_gemm_out(
    const __bf16* __restrict__ A, const __bf16* __restrict__ Wot,
    const float* __restrict__ bo, const float* __restrict__ resid, float* __restrict__ out)
{
  __shared__ __align__(16) __bf16 smem[2 * (128 * 32 + 128 * 32)];  // 32 KB dbuf
  f32x4 acc[4][4];
#pragma unroll
  for (int i = 0; i < 4; ++i)
#pragma unroll
    for (int j = 0; j < 4; ++j)
#pragma unroll
      for (int r = 0; r < 4; ++r) acc[i][j][r] = 0.f;
  const int m0 = blockIdx.x * 128, n0 = blockIdx.y * 128;
  gemm_core_db<128, 128>(A, Wot, 512, m0, n0, smem, acc);

  const int lane = threadIdx.x & 63, wave = threadIdx.x >> 6;
  const int wm = wave >> 1, wn = wave & 1, l15 = lane & 15, l4 = lane >> 4;
#pragma unroll
  for (int mi = 0; mi < 4; ++mi)
#pragma unroll
    for (int ni = 0; ni < 4; ++ni) {
      int gcol = n0 + wn * 64 + ni * 16 + l15;
      float bb = bo[gcol];
#pragma unroll
      for (int r = 0; r < 4; ++r) {
        int grow = m0 + wm * 64 + mi * 16 + l4 * 4 + r;
        size_t idx = (size_t)grow * 512 + gcol;
        out[idx] = acc[mi][ni][r] + bb + resid[idx];
      }
    }
}

// ---------------------------------------------------------------------------
extern "C" void kernel_launch(void* const* d_in, const int* in_sizes, int n_in,
                              void* d_out, int out_size, void* d_ws, size_t ws_size,
                              hipStream_t stream)
{
  const float* x     = (const float*)d_in[0];
  const float* gamma = (const float*)d_in[1];
  const float* beta  = (const float*)d_in[2];
  const float* wq    = (const float*)d_in[3];
  const float* bq    = (const float*)d_in[4];
  const float* wk    = (const float*)d_in[5];
  const float* bk    = (const float*)d_in[6];
  const float* wv    = (const float*)d_in[7];
  const float* bv    = (const float*)d_in[8];
  const float* wo    = (const float*)d_in[9];
  const float* bo    = (const float*)d_in[10];
  float* out = (float*)d_out;

  char* ws = (char*)d_ws;
  size_t off = 0;
  auto alloc = [&](size_t bytes) -> char* {
    char* p = ws + off;
    off += (bytes + 255) & ~(size_t)255;
    return p;
  };
  float*  gns     = (float*)alloc(128 * 4);
  float*  gnss    = (float*)alloc(128 * 4);
  __bf16* x16     = (__bf16*)alloc(16384ull * 512 * 2);   // 16 MB
  __bf16* wqkvt   = (__bf16*)alloc(1536ull * 512 * 2);    // 1.5 MB
  float*  biasqkv = (float*)alloc(1536 * 4);
  __bf16* wot     = (__bf16*)alloc(512ull * 512 * 2);     // 0.5 MB
  float*  lsum    = (float*)alloc(16384ull * 4);          // 64 KB row sums
  unsigned char* q8  = (unsigned char*)alloc(16384ull * 512);     // 8 MB fp8 Q
  unsigned char* k8  = (unsigned char*)alloc(16384ull * 512);     // 8 MB fp8 K
  unsigned char* vt8 = (unsigned char*)alloc(16384ull * 512);     // 8 MB fp8 V^T
  __bf16* attn    = (__bf16*)alloc(16384ull * 512 * 2);   // 16 MB
  unsigned char* S8 = (unsigned char*)alloc(4ull * 4096 * 4096);  // 64 MB fp8 exp(scores)
  // total ~122 MB

  k_prep<<<dim3(4167), dim3(256), 0, stream>>>(wq, bq, wk, bk, wv, bv, wo,
                                               wqkvt, biasqkv, wot, lsum, gns, gnss);
  k_gnstats<<<dim3(1024), dim3(256), 0, stream>>>(x, gns, gnss);
  k_norm<<<dim3(8192), dim3(256), 0, stream>>>(x, gns, gnss, gamma, beta, x16);
  k_gemm_qkv<<<dim3(128, 12), dim3(256), 0, stream>>>(x16, wqkvt, biasqkv, q8, k8, vt8);
  k_gemm_s<<<dim3(32, 32, 4), dim3(256), 0, stream>>>(q8, k8, S8, lsum);
  k_gemm_pv<<<dim3(32, 4, 4), dim3(256), 0, stream>>>(S8, vt8, lsum, attn);
  k_gemm_out<<<dim3(128, 4), dim3(256), 0, stream>>>(attn, wot, bo, x, out);
}

// Round 13
// 294.138 us; speedup vs baseline: 1.0821x; 1.0111x over previous
//
#include <hip/hip_runtime.h>

// ---------------------------------------------------------------------------
// VAEAttention: GroupNorm(32) -> q,k,v 1x1 conv -> full spatial attention
// (N=4096 tokens, d=512) -> out proj -> +residual.   B=4, H=W=64, C=512.
// R19: overhead trims.  (1) k_prep + k_gnstats fused into one launch (k_pre);
// gnstats blocks write per-chunk partials gnp/gnssp (no atomics, no zero-init
// ordering hazard); k_norm sums the 8 partials.  (2) log2(e) folded into the
// q scale; k_gemm_s uses exp2 (v_exp_f32 is natively 2^x) -- drops one v_mul
// per accumulator element.  Cores unchanged from R18 (297.4us).
// ---------------------------------------------------------------------------

typedef __bf16 bf16x8 __attribute__((ext_vector_type(8)));
typedef __bf16 bf16x4 __attribute__((ext_vector_type(4)));
typedef float  f32x4  __attribute__((ext_vector_type(4)));
typedef float  f32x16 __attribute__((ext_vector_type(16)));
typedef int    i32x8  __attribute__((ext_vector_type(8)));

#define GLDS(gp, lp) __builtin_amdgcn_global_load_lds( \
    (const __attribute__((address_space(1))) void*)(gp), \
    (__attribute__((address_space(3))) void*)(lp), 16, 0, 0)

// fp32 -> fp8 e4m3 (OCP on gfx950), RNE via HW cvt. Low byte of packed pair.
__device__ __forceinline__ unsigned char f2fp8(float x) {
  int p = __builtin_amdgcn_cvt_pk_fp8_f32(x, 0.f, 0, false);
  return (unsigned char)(p & 0xff);
}

// ---------------------------------------------------------------------------
// Fused prep + GroupNorm partial stats (independent block ranges).
// Blocks [0, 4167): weight transposes (wq scaled by log2e/sqrt(512)), biases,
//                   lsum zeroing.
// Blocks [4167, 5191): 1024 stat blocks = 8 chunks per (b,g); each reduces
//                   512 pixels x 16 ch and writes gnp/gnssp[bg*8+chunk]
//                   (private slots -> no atomics, no init needed).
// ---------------------------------------------------------------------------
__global__ __launch_bounds__(256) void k_pre(
    const float* __restrict__ wq, const float* __restrict__ bq,
    const float* __restrict__ wk, const float* __restrict__ bk,
    const float* __restrict__ wv, const float* __restrict__ bv,
    const float* __restrict__ wo,
    __bf16* __restrict__ wqkvt, float* __restrict__ biasqkv, __bf16* __restrict__ wot,
    float* __restrict__ lsum,
    const float* __restrict__ x, float* __restrict__ gnp, float* __restrict__ gnssp)
{
  if (blockIdx.x < 4167) {
    // scores GEMM computes exp2(q'.k): fold log2(e) into the q scale.
    const float sc = 0.04419417382415922f * 1.4426950408889634f;  // log2e/sqrt(512)
    int idx = blockIdx.x * 256 + threadIdx.x;
    if (idx < 786432) {
      int d = idx >> 9, c = idx & 511;
      float v;
      if (d < 512)       v = wq[c * 512 + d] * sc;
      else if (d < 1024) v = wk[c * 512 + d - 512];
      else               v = wv[c * 512 + d - 1024];
      wqkvt[idx] = (__bf16)v;
    } else if (idx < 786432 + 262144) {
      int j = idx - 786432;
      int d = j >> 9, c = j & 511;
      wot[j] = (__bf16)wo[c * 512 + d];
    } else if (idx < 786432 + 262144 + 1536) {
      int d = idx - 786432 - 262144;
      float v = (d < 512) ? bq[d] * sc : (d < 1024 ? bk[d - 512] : bv[d - 1024]);
      biasqkv[d] = v;
    } else if (idx < 786432 + 262144 + 1536 + 16384) {
      lsum[idx - 786432 - 262144 - 1536] = 0.f;
    }
  } else {
    const int blk = blockIdx.x - 4167;    // 0..1023
    const int bg = blk >> 3, chunk = blk & 7;
    const int b = bg >> 5, g = bg & 31;
    const float* base = x + (size_t)b * 2097152 + g * 16;
    float s = 0.f, ss = 0.f;
#pragma unroll
    for (int it = 0; it < 2; ++it) {
      int p = chunk * 512 + it * 256 + threadIdx.x;
      const float4* rp = (const float4*)(base + (size_t)p * 512);
#pragma unroll
      for (int j = 0; j < 4; ++j) {
        float4 t = rp[j];
        s  += t.x + t.y + t.z + t.w;
        ss += t.x * t.x + t.y * t.y + t.z * t.z + t.w * t.w;
      }
    }
    for (int off = 32; off; off >>= 1) { s += __shfl_xor(s, off, 64); ss += __shfl_xor(ss, off, 64); }
    __shared__ float rs[4], rss[4];
    if ((threadIdx.x & 63) == 0) { rs[threadIdx.x >> 6] = s; rss[threadIdx.x >> 6] = ss; }
    __syncthreads();
    if (threadIdx.x == 0) {
      gnp[bg * 8 + chunk]   = rs[0] + rs[1] + rs[2] + rs[3];
      gnssp[bg * 8 + chunk] = rss[0] + rss[1] + rss[2] + rss[3];
    }
  }
}

// ---------------------------------------------------------------------------
// Normalize + affine + cast to bf16; finalizes mean/rstd from the 8 partials.
// ---------------------------------------------------------------------------
__global__ __launch_bounds__(256) void k_norm(
    const float* __restrict__ x, const float* __restrict__ gnp,
    const float* __restrict__ gnssp, const float* __restrict__ gamma,
    const float* __restrict__ beta, __bf16* __restrict__ x16)
{
  size_t i4 = (size_t)blockIdx.x * 256 + threadIdx.x;  // 0..2097151
  size_t i = i4 * 4;
  int c = (int)(i & 511);
  int bg = (int)(i >> 21) * 32 + (c >> 4);
  float s = 0.f, ss = 0.f;
#pragma unroll
  for (int j = 0; j < 8; ++j) { s += gnp[bg * 8 + j]; ss += gnssp[bg * 8 + j]; }
  float m = s * (1.f / 65536.f);
  float var = ss * (1.f / 65536.f) - m * m;
  float r = rsqrtf(var + 1e-6f);
  float4 xv = *(const float4*)(x + i);
  float4 gv = *(const float4*)(gamma + c);
  float4 bv = *(const float4*)(beta + c);
  bf16x4 o;
  o[0] = (__bf16)((xv.x - m) * r * gv.x + bv.x);
  o[1] = (__bf16)((xv.y - m) * r * gv.y + bv.y);
  o[2] = (__bf16)((xv.z - m) * r * gv.z + bv.z);
  o[3] = (__bf16)((xv.w - m) * r * gv.w + bv.w);
  *(bf16x4*)(x16 + i) = o;
}

// ---------------------------------------------------------------------------
// GEMM core (bf16, XOR-swizzled LDS, 2-phase double-buffer):
// prologue stages tile 0; per tile: STAGE(t+1) -> ds_read+MFMA(t) -> ONE
// barrier (R14-verified).
// ---------------------------------------------------------------------------
template <int BM, int BN>
__device__ __forceinline__ void gemm_core_db(
    const __bf16* __restrict__ A, const __bf16* __restrict__ Bt, int K,
    int m0, int n0, __bf16* smem, f32x4 (&acc)[BM / 32][BN / 32])
{
  constexpr int FM = BM / 32, FN = BN / 32;
  constexpr int ASZ = BM * 32;          // elements per A tile (BM x 32)
  constexpr int BSZ = BN * 32;
  constexpr int BUF = ASZ + BSZ;
  const int tid = threadIdx.x;
  const int lane = tid & 63;
  const int wave = tid >> 6;
  const int wm = wave >> 1, wn = wave & 1;
  const int l15 = lane & 15, l4 = lane >> 4;
  const int sw = (l15 >> 1) & 3;            // read-side chunk swizzle
  const int nt = K >> 5;

  auto stage = [&](int b, int kt) {
    __bf16* As_ = smem + b * BUF;
    __bf16* Bs_ = As_ + ASZ;
#pragma unroll
    for (int i = 0; i < BM / 64; ++i) {
      int ci = i * 256 + tid;
      int row = ci >> 2, kc = ci & 3;
      int kcs = kc ^ ((row >> 1) & 3);       // swizzled source chunk
      GLDS(A + (size_t)(m0 + row) * K + kt + kcs * 8, As_ + i * 2048 + wave * 512);
    }
#pragma unroll
    for (int i = 0; i < BN / 64; ++i) {
      int ci = i * 256 + tid;
      int row = ci >> 2, kc = ci & 3;
      int kcs = kc ^ ((row >> 1) & 3);
      GLDS(Bt + (size_t)(n0 + row) * K + kt + kcs * 8, Bs_ + i * 2048 + wave * 512);
    }
  };

  stage(0, 0);
  __syncthreads();                       // tile 0 valid
  for (int t = 0; t < nt; ++t) {
    if (t + 1 < nt) stage((t + 1) & 1, (t + 1) * 32);
    const __bf16* As = smem + (t & 1) * BUF;
    const __bf16* Bs = As + ASZ;
    bf16x8 af[FM], bfr[FN];
#pragma unroll
    for (int mi = 0; mi < FM; ++mi)
      af[mi] = *(const bf16x8*)&As[(wm * (BM / 2) + mi * 16 + l15) * 32 + (l4 ^ sw) * 8];
#pragma unroll
    for (int ni = 0; ni < FN; ++ni)
      bfr[ni] = *(const bf16x8*)&Bs[(wn * (BN / 2) + ni * 16 + l15) * 32 + (l4 ^ sw) * 8];
#pragma unroll
    for (int mi = 0; mi < FM; ++mi)
#pragma unroll
      for (int ni = 0; ni < FN; ++ni)
        acc[mi][ni] = __builtin_amdgcn_mfma_f32_16x16x32_bf16(af[mi], bfr[ni], acc[mi][ni], 0, 0, 0);
    __syncthreads();  // t+1 loads drained; buf[t&1] reads done before overwrite
  }
}

// ---------------------------------------------------------------------------
// GEMM core (fp8 x fp8, BK=64, XOR-swizzled, 2-phase double-buffer):
// R12/R14-verified (VGPR 80-84 on k_gemm_s).
// ---------------------------------------------------------------------------
template <int BM, int BN>
__device__ __forceinline__ void gemm_core_fp8_db(
    const unsigned char* __restrict__ A, const unsigned char* __restrict__ Bt,
    int K, int m0, int n0, unsigned char* smem,
    f32x4 (&acc)[BM / 32][BN / 32])
{
  constexpr int FM = BM / 32, FN = BN / 32;
  constexpr int ASZ = (BM / 64) * 4096;   // A tile bytes (BM x 64)
  constexpr int BSZ = (BN / 64) * 4096;
  constexpr int BUF = ASZ + BSZ;
  const int tid = threadIdx.x;
  const int lane = tid & 63;
  const int wave = tid >> 6;
  const int wm = wave >> 1, wn = wave & 1;
  const int l15 = lane & 15, l4 = lane >> 4;
  const int sw = (l15 >> 1) & 3;
  const int h8 = (l4 & 1) * 8;      // 8B half within a 16B chunk
  const int nt = K >> 6;

  auto stage = [&](int b, int kt) {
    unsigned char* As_ = smem + b * BUF;
    unsigned char* Bs_ = As_ + ASZ;
#pragma unroll
    for (int i = 0; i < BM / 64; ++i) {
      int ci = i * 256 + tid;
      int row = ci >> 2, kc = ci & 3;
      int kcs = (kc ^ ((row >> 1) & 3)) * 16;  // swizzled 16B source chunk
      GLDS(A + (size_t)(m0 + row) * K + kt + kcs, As_ + i * 4096 + wave * 1024);
    }
#pragma unroll
    for (int i = 0; i < BN / 64; ++i) {
      int ci = i * 256 + tid;
      int row = ci >> 2, kc = ci & 3;
      int kcs = (kc ^ ((row >> 1) & 3)) * 16;
      GLDS(Bt + (size_t)(n0 + row) * K + kt + kcs, Bs_ + i * 4096 + wave * 1024);
    }
  };

  stage(0, 0);
  __syncthreads();                       // tile 0 valid
  for (int t = 0; t < nt; ++t) {
    if (t + 1 < nt) stage((t + 1) & 1, (t + 1) * 64);
    const unsigned char* As = smem + (t & 1) * BUF;
    const unsigned char* Bs = As + ASZ;
    long long af[FM][2], bfr[FN][2];
#pragma unroll
    for (int mi = 0; mi < FM; ++mi) {
      int row = wm * (BM / 2) + mi * 16 + l15;
#pragma unroll
      for (int j = 0; j < 2; ++j) {
        int G = j * 2 + (l4 >> 1);           // global 16B-chunk index
        af[mi][j] = *(const long long*)&As[row * 64 + ((G ^ sw) << 4) + h8];
      }
    }
#pragma unroll
    for (int ni = 0; ni < FN; ++ni) {
      int row = wn * (BN / 2) + ni * 16 + l15;
#pragma unroll
      for (int j = 0; j < 2; ++j) {
        int G = j * 2 + (l4 >> 1);
        bfr[ni][j] = *(const long long*)&Bs[row * 64 + ((G ^ sw) << 4) + h8];
      }
    }
#pragma unroll
    for (int mi = 0; mi < FM; ++mi)
#pragma unroll
      for (int ni = 0; ni < FN; ++ni) {
        f32x4 c = acc[mi][ni];
        c = __builtin_amdgcn_mfma_f32_16x16x32_fp8_fp8(af[mi][0], bfr[ni][0], c, 0, 0, 0);
        c = __builtin_amdgcn_mfma_f32_16x16x32_fp8_fp8(af[mi][1], bfr[ni][1], c, 0, 0, 0);
        acc[mi][ni] = c;
      }
    __syncthreads();  // t+1 loads drained; buf[t&1] reads done before overwrite
  }
}

// ---------------------------------------------------------------------------
// GEMM core (MX fp8, 32x32x64, scale=1.0, 3-buffer COUNTED-VMCNT pipeline):
// per tile: stage(t+2) -> s_waitcnt vmcnt(8) -> s_barrier -> ds_read+MFMA ->
// s_barrier.  (R18-verified, neutral-vs-dbuf but correct; PV is HBM-floor.)
// A-operand: lane l holds row (l&31), k-bytes [ (l>>5)*32 , +32 ).
// C/D (m74/m101): col = lane&31, row = (r&3)+8*(r>>2)+4*(l>>5).
// ---------------------------------------------------------------------------
template <int BM, int BN>
__device__ __forceinline__ void gemm_core_mx32_p3(
    const unsigned char* __restrict__ A, const unsigned char* __restrict__ Bt,
    int K, int m0, int n0, unsigned char* smem,
    f32x16 (&acc)[BM / 64][BN / 64])
{
  constexpr int FM = BM / 64, FN = BN / 64;
  constexpr int ASZ = (BM / 64) * 4096;
  constexpr int BSZ = (BN / 64) * 4096;
  constexpr int BUF = ASZ + BSZ;
  const int tid = threadIdx.x;
  const int lane = tid & 63;
  const int wave = tid >> 6;
  const int wm = wave >> 1, wn = wave & 1;
  const int l31 = lane & 31, h = lane >> 5;   // h: k-block of 32 bytes
  const int nt = K >> 6;

  auto stage = [&](int b, int t) {
    const int kt = t * 64;
    unsigned char* As_ = smem + b * BUF;
    unsigned char* Bs_ = As_ + ASZ;
#pragma unroll
    for (int i = 0; i < BM / 64; ++i) {
      int ci = i * 256 + tid;
      int row = ci >> 2, kc = ci & 3;
      int kcs = (kc ^ ((row >> 1) & 3)) * 16;
      GLDS(A + (size_t)(m0 + row) * K + kt + kcs, As_ + i * 4096 + wave * 1024);
    }
#pragma unroll
    for (int i = 0; i < BN / 64; ++i) {
      int ci = i * 256 + tid;
      int row = ci >> 2, kc = ci & 3;
      int kcs = (kc ^ ((row >> 1) & 3)) * 16;
      GLDS(Bt + (size_t)(n0 + row) * K + kt + kcs, Bs_ + i * 4096 + wave * 1024);
    }
  };

  stage(0, 0);
  stage(1, 1);
  int cb = 0, sb = 2;                    // compute buffer / stage buffer
  for (int t = 0; t < nt; ++t) {
    if (t + 2 < nt) stage(sb, t + 2);
    // Drain own stage-t loads; keep stages t+1 (and t+2 if issued) in flight.
    if (t + 2 < nt)      asm volatile("s_waitcnt vmcnt(8)" ::: "memory");
    else if (t + 1 < nt) asm volatile("s_waitcnt vmcnt(4)" ::: "memory");
    else                 asm volatile("s_waitcnt vmcnt(0)" ::: "memory");
    __builtin_amdgcn_s_barrier();        // all waves' t-loads landed
    __builtin_amdgcn_sched_barrier(0);
    const unsigned char* As = smem + cb * BUF;
    const unsigned char* Bs = As + ASZ;
    i32x8 af[FM], bfr[FN];
#pragma unroll
    for (int mi = 0; mi < FM; ++mi) {
      int row = wm * (BM / 2) + mi * 32 + l31;
      int s = (row >> 1) & 3;
      int c0 = (2 * h) ^ s, c1 = (2 * h + 1) ^ s;   // two 16B chunks = 32B of k
      uint4 u0 = *(const uint4*)&As[row * 64 + c0 * 16];
      uint4 u1 = *(const uint4*)&As[row * 64 + c1 * 16];
      af[mi][0] = (int)u0.x; af[mi][1] = (int)u0.y; af[mi][2] = (int)u0.z; af[mi][3] = (int)u0.w;
      af[mi][4] = (int)u1.x; af[mi][5] = (int)u1.y; af[mi][6] = (int)u1.z; af[mi][7] = (int)u1.w;
    }
#pragma unroll
    for (int ni = 0; ni < FN; ++ni) {
      int row = wn * (BN / 2) + ni * 32 + l31;
      int s = (row >> 1) & 3;
      int c0 = (2 * h) ^ s, c1 = (2 * h + 1) ^ s;
      uint4 u0 = *(const uint4*)&Bs[row * 64 + c0 * 16];
      uint4 u1 = *(const uint4*)&Bs[row * 64 + c1 * 16];
      bfr[ni][0] = (int)u0.x; bfr[ni][1] = (int)u0.y; bfr[ni][2] = (int)u0.z; bfr[ni][3] = (int)u0.w;
      bfr[ni][4] = (int)u1.x; bfr[ni][5] = (int)u1.y; bfr[ni][6] = (int)u1.z; bfr[ni][7] = (int)u1.w;
    }
#pragma unroll
    for (int mi = 0; mi < FM; ++mi)
#pragma unroll
      for (int ni = 0; ni < FN; ++ni)
        acc[mi][ni] = __builtin_amdgcn_mfma_scale_f32_32x32x64_f8f6f4(
            af[mi], bfr[ni], acc[mi][ni],
            0, 0,                       // cbsz/blgp = fp8 e4m3
            0, 0x7f7f7f7f,              // scale_a: e8m0 = 1.0
            0, 0x7f7f7f7f);             // scale_b: e8m0 = 1.0
    __builtin_amdgcn_sched_barrier(0);   // ds_reads complete before barrier
    __builtin_amdgcn_s_barrier();        // readers of buf cb done; cb is the
    __builtin_amdgcn_sched_barrier(0);   // buffer staged at iter t+1
    cb = (cb == 2) ? 0 : cb + 1;
    sb = (sb == 2) ? 0 : sb + 1;
  }
}

// fp8 16x16 C/D layout (measured m89/m91): col = lane&15, row = (lane>>4)*4 + reg.

// ---------------------------------------------------------------------------
// QKV GEMM: X[16384][512] @ Wqkv^T.  All outputs staged in LDS and written
// as coalesced 16B chunks: q8/k8 as [token][c] rows, v transposed to
// vt8[b][c][n] rows.  Bias folded into the staging conversion.  (R15-verified)
// ---------------------------------------------------------------------------
__global__ __launch_bounds__(256) void k_gemm_qkv(
    const __bf16* __restrict__ X, const __bf16* __restrict__ Wt,
    const float* __restrict__ bias, unsigned char* __restrict__ q8,
    unsigned char* __restrict__ k8, unsigned char* __restrict__ vt8)
{
  __shared__ __align__(16) __bf16 smem[2 * (128 * 32 + 128 * 32)];  // 32 KB dbuf
  f32x4 acc[4][4];
#pragma unroll
  for (int i = 0; i < 4; ++i)
#pragma unroll
    for (int j = 0; j < 4; ++j)
#pragma unroll
      for (int r = 0; r < 4; ++r) acc[i][j][r] = 0.f;
  const int m0 = blockIdx.x * 128, n0 = blockIdx.y * 128;
  gemm_core_db<128, 128>(X, Wt, 512, m0, n0, smem, acc);

  const int lane = threadIdx.x & 63, wave = threadIdx.x >> 6;
  const int wm = wave >> 1, wn = wave & 1, l15 = lane & 15, l4 = lane >> 4;

  // Stage the 128x128 fp8 patch in LDS (stride 144), then store coalesced.
  unsigned char* t8 = (unsigned char*)smem;  // 128*144 = 18432 B <= 32768
  if (blockIdx.y < 8) {
    // q or k: patch[token_local][c_local], no transpose
#pragma unroll
    for (int mi = 0; mi < 4; ++mi)
#pragma unroll
      for (int ni = 0; ni < 4; ++ni) {
        int lcol = wn * 64 + ni * 16 + l15;
        float bb = bias[n0 + lcol];
#pragma unroll
        for (int r = 0; r < 4; ++r) {
          int lrow = wm * 64 + mi * 16 + l4 * 4 + r;
          t8[lrow * 144 + lcol] = f2fp8(acc[mi][ni][r] + bb);
        }
      }
    __syncthreads();
    unsigned char* dst = (blockIdx.y < 4) ? q8 : k8;
    const int c0 = (blockIdx.y < 4) ? n0 : n0 - 512;
#pragma unroll
    for (int j = 0; j < 4; ++j) {
      int idx = j * 256 + threadIdx.x;
      int crow = idx >> 3, ccol = (idx & 7) * 16;
      uint4 v = *(const uint4*)&t8[crow * 144 + ccol];
      *(uint4*)&dst[(size_t)(m0 + crow) * 512 + c0 + ccol] = v;
    }
  } else {
    // v: patch transposed to [c_local][token_local]
#pragma unroll
    for (int mi = 0; mi < 4; ++mi)
#pragma unroll
      for (int ni = 0; ni < 4; ++ni) {
        int c_l = wn * 64 + ni * 16 + l15;
        float bb = bias[n0 + c_l];
#pragma unroll
        for (int r = 0; r < 4; ++r) {
          int n_l = wm * 64 + mi * 16 + l4 * 4 + r;
          t8[c_l * 144 + n_l] = f2fp8(acc[mi][ni][r] + bb);
        }
      }
    __syncthreads();
    const int b = m0 >> 12, nst = m0 & 4095;
    const int c0 = n0 - 1024;
#pragma unroll
    for (int j = 0; j < 4; ++j) {
      int idx = j * 256 + threadIdx.x;
      int crow = idx >> 3, ccol = (idx & 7) * 16;
      uint4 v = *(const uint4*)&t8[crow * 144 + ccol];
      *(uint4*)&vt8[((size_t)b * 512 + c0 + crow) * 4096 + nst + ccol] = v;
    }
  }
}

// ---------------------------------------------------------------------------
// Scores GEMM (fp8 x fp8, BK=64, 2-phase dbuf) + max-free softmax numerator,
// batched over z: P[b][n][m] = exp2(q'.k) stored fp8 e4m3 (log2e folded into
// q' at prep); lsum fp32 row sums.  Epilogue: exp2+rowsum in regs, ONE-pass
// staging into 128x144 LDS tile, 16B-coalesced stores.
// ---------------------------------------------------------------------------
__global__ __launch_bounds__(256) void k_gemm_s(
    const unsigned char* __restrict__ qall, const unsigned char* __restrict__ kall,
    unsigned char* __restrict__ S8all, float* __restrict__ lsum)
{
  __shared__ __align__(16) unsigned char smem[32768];  // 2 x (8KB As + 8KB Bs)
  f32x4 acc[4][4];
#pragma unroll
  for (int i = 0; i < 4; ++i)
#pragma unroll
    for (int j = 0; j < 4; ++j)
#pragma unroll
      for (int r = 0; r < 4; ++r) acc[i][j][r] = 0.f;

  // supertile swizzle: 1024 blocks/batch -> 16 groups of 64 (8x8)
  const int b = blockIdx.z;
  const int flat = blockIdx.x + (blockIdx.y << 5);
  const int gx = flat & 7, gy = (flat >> 3) & 7, grp = flat >> 6;
  const int bx = (grp & 3) * 8 + gx, by = (grp >> 2) * 8 + gy;
  const int m0 = bx * 128, n0 = by * 128;

  const unsigned char* q = qall + (size_t)b * 4096 * 512;
  const unsigned char* k = kall + (size_t)b * 4096 * 512;
  unsigned char* S8 = S8all + (size_t)b * 4096 * 4096;
  gemm_core_fp8_db<128, 128>(q, k, 512, m0, n0, smem, acc);

  const int lane = threadIdx.x & 63, wave = threadIdx.x >> 6;
  const int wm = wave >> 1, wn = wave & 1, l15 = lane & 15, l4 = lane >> 4;

  // exp2 in place + fp32 row-sum atomics (pre-fp8-rounding; unbiased)
#pragma unroll
  for (int mi = 0; mi < 4; ++mi) {
    float rsum[4] = {0.f, 0.f, 0.f, 0.f};
#pragma unroll
    for (int ni = 0; ni < 4; ++ni)
#pragma unroll
      for (int r = 0; r < 4; ++r) {
        float p = __builtin_exp2f(acc[mi][ni][r]);
        acc[mi][ni][r] = p;
        rsum[r] += p;
      }
#pragma unroll
    for (int r = 0; r < 4; ++r) {
#pragma unroll
      for (int off = 1; off < 16; off <<= 1) rsum[r] += __shfl_xor(rsum[r], off, 64);
      if (l15 == 0) {
        int grow = m0 + wm * 64 + mi * 16 + l4 * 4 + r;
        atomicAdd(&lsum[b * 4096 + grow], rsum[r]);
      }
    }
  }

  // One-pass staging: all waves convert into t8[128][144], then store.
  unsigned char* t8 = smem;  // 128*144 = 18432 B <= 32768
#pragma unroll
  for (int mi = 0; mi < 4; ++mi)
#pragma unroll
    for (int ni = 0; ni < 4; ++ni) {
      int lcol = wn * 64 + ni * 16 + l15;
#pragma unroll
      for (int r = 0; r < 4; ++r) {
        int lrow = wm * 64 + mi * 16 + l4 * 4 + r;
        t8[lrow * 144 + lcol] = f2fp8(acc[mi][ni][r]);
      }
    }
  __syncthreads();
  // store 128 rows x 128 B: 1024 chunks of 16B, 4 per thread
#pragma unroll
  for (int j = 0; j < 4; ++j) {
    int idx = j * 256 + threadIdx.x;
    int crow = idx >> 3, ccol = (idx & 7) * 16;
    uint4 v = *(const uint4*)&t8[crow * 144 + ccol];
    *(uint4*)&S8[(size_t)(m0 + crow) * 4096 + n0 + ccol] = v;
  }
}

// ---------------------------------------------------------------------------
// PV GEMM (MX fp8 32x32x64, BK=64, 3-buffer counted-vmcnt pipeline, 128x128),
// batched over z: O[b,n,c] = (sum_m P[b,n,m] * vt[b,c,m]) / l[b,n].
// ---------------------------------------------------------------------------
__global__ __launch_bounds__(256) void k_gemm_pv(
    const unsigned char* __restrict__ S8all, const unsigned char* __restrict__ vt8all,
    const float* __restrict__ lsum, __bf16* __restrict__ attn)
{
  __shared__ __align__(16) unsigned char smem[49152];  // 3 x (8KB As + 8KB Bs)
  f32x16 acc[2][2];
#pragma unroll
  for (int i = 0; i < 2; ++i)
#pragma unroll
    for (int j = 0; j < 2; ++j)
#pragma unroll
      for (int r = 0; r < 16; ++r) acc[i][j][r] = 0.f;
  const int b = blockIdx.z;
  const unsigned char* P = S8all + (size_t)b * 4096 * 4096;
  const unsigned char* V = vt8all + (size_t)b * 512 * 4096;
  __bf16* O = attn + (size_t)b * 4096 * 512;
  const int m0 = blockIdx.x * 128, n0 = blockIdx.y * 128;
  gemm_core_mx32_p3<128, 128>(P, V, 4096, m0, n0, smem, acc);

  const int lane = threadIdx.x & 63, wave = threadIdx.x >> 6;
  const int wm = wave >> 1, wn = wave & 1, l31 = lane & 31, h = lane >> 5;
#pragma unroll
  for (int mi = 0; mi < 2; ++mi)
#pragma unroll
    for (int ni = 0; ni < 2; ++ni) {
      int gcol = n0 + wn * 64 + ni * 32 + l31;
#pragma unroll
      for (int r = 0; r < 16; ++r) {
        int grow = m0 + wm * 64 + mi * 32 + (r & 3) + 8 * (r >> 2) + 4 * h;
        float inv = 1.f / lsum[b * 4096 + grow];
        O[(size_t)grow * 512 + gcol] = (__bf16)(acc[mi][ni][r] * inv);
      }
    }
}

// ---------------------------------------------------------------------------
// Output projection + bias + residual, fp32 store to d_out.
// ---------------------------------------------------------------------------
__global__ __launch_bounds__(256) void k_gemm_out(
    const __bf16* __restrict__ A, const __bf16* __restrict__ Wot,
    const float* __restrict__ bo, const float* __restrict__ resid, float* __restrict__ out)
{
  __shared__ __align__(16) __bf16 smem[2 * (128 * 32 + 128 * 32)];  // 32 KB dbuf
  f32x4 acc[4][4];
#pragma unroll
  for (int i = 0; i < 4; ++i)
#pragma unroll
    for (int j = 0; j < 4; ++j)
#pragma unroll
      for (int r = 0; r < 4; ++r) acc[i][j][r] = 0.f;
  const int m0 = blockIdx.x * 128, n0 = blockIdx.y * 128;
  gemm_core_db<128, 128>(A, Wot, 512, m0, n0, smem, acc);

  const int lane = threadIdx.x & 63, wave = threadIdx.x >> 6;
  const int wm = wave >> 1, wn = wave & 1, l15 = lane & 15, l4 = lane >> 4;
#pragma unroll
  for (int mi = 0; mi < 4; ++mi)
#pragma unroll
    for (int ni = 0; ni < 4; ++ni) {
      int gcol = n0 + wn * 64 + ni * 16 + l15;
      float bb = bo[gcol];
#pragma unroll
      for (int r = 0; r < 4; ++r) {
        int grow = m0 + wm * 64 + mi * 16 + l4 * 4 + r;
        size_t idx = (size_t)grow * 512 + gcol;
        out[idx] = acc[mi][ni][r] + bb + resid[idx];
      }
    }
}

// ---------------------------------------------------------------------------
extern "C" void kernel_launch(void* const* d_in, const int* in_sizes, int n_in,
                              void* d_out, int out_size, void* d_ws, size_t ws_size,
                              hipStream_t stream)
{
  const float* x     = (const float*)d_in[0];
  const float* gamma = (const float*)d_in[1];
  const float* beta  = (const float*)d_in[2];
  const float* wq    = (const float*)d_in[3];
  const float* bq    = (const float*)d_in[4];
  const float* wk    = (const float*)d_in[5];
  const float* bk    = (const float*)d_in[6];
  const float* wv    = (const float*)d_in[7];
  const float* bv    = (const float*)d_in[8];
  const float* wo    = (const float*)d_in[9];
  const float* bo    = (const float*)d_in[10];
  float* out = (float*)d_out;

  char* ws = (char*)d_ws;
  size_t off = 0;
  auto alloc = [&](size_t bytes) -> char* {
    char* p = ws + off;
    off += (bytes + 255) & ~(size_t)255;
    return p;
  };
  float*  gnp     = (float*)alloc(1024 * 4);
  float*  gnssp   = (float*)alloc(1024 * 4);
  __bf16* x16     = (__bf16*)alloc(16384ull * 512 * 2);   // 16 MB
  __bf16* wqkvt   = (__bf16*)alloc(1536ull * 512 * 2);    // 1.5 MB
  float*  biasqkv = (float*)alloc(1536 * 4);
  __bf16* wot     = (__bf16*)alloc(512ull * 512 * 2);     // 0.5 MB
  float*  lsum    = (float*)alloc(16384ull * 4);          // 64 KB row sums
  unsigned char* q8  = (unsigned char*)alloc(16384ull * 512);     // 8 MB fp8 Q
  unsigned char* k8  = (unsigned char*)alloc(16384ull * 512);     // 8 MB fp8 K
  unsigned char* vt8 = (unsigned char*)alloc(16384ull * 512);     // 8 MB fp8 V^T
  __bf16* attn    = (__bf16*)alloc(16384ull * 512 * 2);   // 16 MB
  unsigned char* S8 = (unsigned char*)alloc(4ull * 4096 * 4096);  // 64 MB fp8 exp(scores)
  // total ~122 MB

  k_pre<<<dim3(5191), dim3(256), 0, stream>>>(wq, bq, wk, bk, wv, bv, wo,
                                              wqkvt, biasqkv, wot, lsum,
                                              x, gnp, gnssp);
  k_norm<<<dim3(8192), dim3(256), 0, stream>>>(x, gnp, gnssp, gamma, beta, x16);
  k_gemm_qkv<<<dim3(128, 12), dim3(256), 0, stream>>>(x16, wqkvt, biasqkv, q8, k8, vt8);
  k_gemm_s<<<dim3(32, 32, 4), dim3(256), 0, stream>>>(q8, k8, S8, lsum);
  k_gemm_pv<<<dim3(32, 4, 4), dim3(256), 0, stream>>>(S8, vt8, lsum, attn);
  k_gemm_out<<<dim3(128, 4), dim3(256), 0, stream>>>(attn, wot, bo, x, out);
}

// Round 14
// 288.586 us; speedup vs baseline: 1.1029x; 1.0192x over previous
//
#include <hip/hip_runtime.h>

// ---------------------------------------------------------------------------
// VAEAttention: GroupNorm(32) -> q,k,v 1x1 conv -> full spatial attention
// (N=4096 tokens, d=512) -> out proj -> +residual.   B=4, H=W=64, C=512.
// R20: fix R19's exp2 sub-regression.  __builtin_exp2f lowered to guarded
// libm exp2f (VALUBusy 33->40, VGPR 80->84, k_gemm_s 81.4->85.0us).  Use
// __builtin_amdgcn_exp2f = raw v_exp_f32 (D = 2^S0): exactly one VALU op
// per accumulator element (log2e pre-folded into the q scale at k_pre).
// Everything else identical to R19 (294.1us).
// ---------------------------------------------------------------------------

typedef __bf16 bf16x8 __attribute__((ext_vector_type(8)));
typedef __bf16 bf16x4 __attribute__((ext_vector_type(4)));
typedef float  f32x4  __attribute__((ext_vector_type(4)));
typedef float  f32x16 __attribute__((ext_vector_type(16)));
typedef int    i32x8  __attribute__((ext_vector_type(8)));

#define GLDS(gp, lp) __builtin_amdgcn_global_load_lds( \
    (const __attribute__((address_space(1))) void*)(gp), \
    (__attribute__((address_space(3))) void*)(lp), 16, 0, 0)

// fp32 -> fp8 e4m3 (OCP on gfx950), RNE via HW cvt. Low byte of packed pair.
__device__ __forceinline__ unsigned char f2fp8(float x) {
  int p = __builtin_amdgcn_cvt_pk_fp8_f32(x, 0.f, 0, false);
  return (unsigned char)(p & 0xff);
}

// ---------------------------------------------------------------------------
// Fused prep + GroupNorm partial stats (independent block ranges).
// Blocks [0, 4167): weight transposes (wq scaled by log2e/sqrt(512)), biases,
//                   lsum zeroing.
// Blocks [4167, 5191): 1024 stat blocks = 8 chunks per (b,g); each reduces
//                   512 pixels x 16 ch and writes gnp/gnssp[bg*8+chunk]
//                   (private slots -> no atomics, no init needed).
// ---------------------------------------------------------------------------
__global__ __launch_bounds__(256) void k_pre(
    const float* __restrict__ wq, const float* __restrict__ bq,
    const float* __restrict__ wk, const float* __restrict__ bk,
    const float* __restrict__ wv, const float* __restrict__ bv,
    const float* __restrict__ wo,
    __bf16* __restrict__ wqkvt, float* __restrict__ biasqkv, __bf16* __restrict__ wot,
    float* __restrict__ lsum,
    const float* __restrict__ x, float* __restrict__ gnp, float* __restrict__ gnssp)
{
  if (blockIdx.x < 4167) {
    // scores GEMM computes exp2(q'.k): fold log2(e) into the q scale.
    const float sc = 0.04419417382415922f * 1.4426950408889634f;  // log2e/sqrt(512)
    int idx = blockIdx.x * 256 + threadIdx.x;
    if (idx < 786432) {
      int d = idx >> 9, c = idx & 511;
      float v;
      if (d < 512)       v = wq[c * 512 + d] * sc;
      else if (d < 1024) v = wk[c * 512 + d - 512];
      else               v = wv[c * 512 + d - 1024];
      wqkvt[idx] = (__bf16)v;
    } else if (idx < 786432 + 262144) {
      int j = idx - 786432;
      int d = j >> 9, c = j & 511;
      wot[j] = (__bf16)wo[c * 512 + d];
    } else if (idx < 786432 + 262144 + 1536) {
      int d = idx - 786432 - 262144;
      float v = (d < 512) ? bq[d] * sc : (d < 1024 ? bk[d - 512] : bv[d - 1024]);
      biasqkv[d] = v;
    } else if (idx < 786432 + 262144 + 1536 + 16384) {
      lsum[idx - 786432 - 262144 - 1536] = 0.f;
    }
  } else {
    const int blk = blockIdx.x - 4167;    // 0..1023
    const int bg = blk >> 3, chunk = blk & 7;
    const int b = bg >> 5, g = bg & 31;
    const float* base = x + (size_t)b * 2097152 + g * 16;
    float s = 0.f, ss = 0.f;
#pragma unroll
    for (int it = 0; it < 2; ++it) {
      int p = chunk * 512 + it * 256 + threadIdx.x;
      const float4* rp = (const float4*)(base + (size_t)p * 512);
#pragma unroll
      for (int j = 0; j < 4; ++j) {
        float4 t = rp[j];
        s  += t.x + t.y + t.z + t.w;
        ss += t.x * t.x + t.y * t.y + t.z * t.z + t.w * t.w;
      }
    }
    for (int off = 32; off; off >>= 1) { s += __shfl_xor(s, off, 64); ss += __shfl_xor(ss, off, 64); }
    __shared__ float rs[4], rss[4];
    if ((threadIdx.x & 63) == 0) { rs[threadIdx.x >> 6] = s; rss[threadIdx.x >> 6] = ss; }
    __syncthreads();
    if (threadIdx.x == 0) {
      gnp[bg * 8 + chunk]   = rs[0] + rs[1] + rs[2] + rs[3];
      gnssp[bg * 8 + chunk] = rss[0] + rss[1] + rss[2] + rss[3];
    }
  }
}

// ---------------------------------------------------------------------------
// Normalize + affine + cast to bf16; finalizes mean/rstd from the 8 partials.
// ---------------------------------------------------------------------------
__global__ __launch_bounds__(256) void k_norm(
    const float* __restrict__ x, const float* __restrict__ gnp,
    const float* __restrict__ gnssp, const float* __restrict__ gamma,
    const float* __restrict__ beta, __bf16* __restrict__ x16)
{
  size_t i4 = (size_t)blockIdx.x * 256 + threadIdx.x;  // 0..2097151
  size_t i = i4 * 4;
  int c = (int)(i & 511);
  int bg = (int)(i >> 21) * 32 + (c >> 4);
  float s = 0.f, ss = 0.f;
#pragma unroll
  for (int j = 0; j < 8; ++j) { s += gnp[bg * 8 + j]; ss += gnssp[bg * 8 + j]; }
  float m = s * (1.f / 65536.f);
  float var = ss * (1.f / 65536.f) - m * m;
  float r = rsqrtf(var + 1e-6f);
  float4 xv = *(const float4*)(x + i);
  float4 gv = *(const float4*)(gamma + c);
  float4 bv = *(const float4*)(beta + c);
  bf16x4 o;
  o[0] = (__bf16)((xv.x - m) * r * gv.x + bv.x);
  o[1] = (__bf16)((xv.y - m) * r * gv.y + bv.y);
  o[2] = (__bf16)((xv.z - m) * r * gv.z + bv.z);
  o[3] = (__bf16)((xv.w - m) * r * gv.w + bv.w);
  *(bf16x4*)(x16 + i) = o;
}

// ---------------------------------------------------------------------------
// GEMM core (bf16, XOR-swizzled LDS, 2-phase double-buffer):
// prologue stages tile 0; per tile: STAGE(t+1) -> ds_read+MFMA(t) -> ONE
// barrier (R14-verified).
// ---------------------------------------------------------------------------
template <int BM, int BN>
__device__ __forceinline__ void gemm_core_db(
    const __bf16* __restrict__ A, const __bf16* __restrict__ Bt, int K,
    int m0, int n0, __bf16* smem, f32x4 (&acc)[BM / 32][BN / 32])
{
  constexpr int FM = BM / 32, FN = BN / 32;
  constexpr int ASZ = BM * 32;          // elements per A tile (BM x 32)
  constexpr int BSZ = BN * 32;
  constexpr int BUF = ASZ + BSZ;
  const int tid = threadIdx.x;
  const int lane = tid & 63;
  const int wave = tid >> 6;
  const int wm = wave >> 1, wn = wave & 1;
  const int l15 = lane & 15, l4 = lane >> 4;
  const int sw = (l15 >> 1) & 3;            // read-side chunk swizzle
  const int nt = K >> 5;

  auto stage = [&](int b, int kt) {
    __bf16* As_ = smem + b * BUF;
    __bf16* Bs_ = As_ + ASZ;
#pragma unroll
    for (int i = 0; i < BM / 64; ++i) {
      int ci = i * 256 + tid;
      int row = ci >> 2, kc = ci & 3;
      int kcs = kc ^ ((row >> 1) & 3);       // swizzled source chunk
      GLDS(A + (size_t)(m0 + row) * K + kt + kcs * 8, As_ + i * 2048 + wave * 512);
    }
#pragma unroll
    for (int i = 0; i < BN / 64; ++i) {
      int ci = i * 256 + tid;
      int row = ci >> 2, kc = ci & 3;
      int kcs = kc ^ ((row >> 1) & 3);
      GLDS(Bt + (size_t)(n0 + row) * K + kt + kcs * 8, Bs_ + i * 2048 + wave * 512);
    }
  };

  stage(0, 0);
  __syncthreads();                       // tile 0 valid
  for (int t = 0; t < nt; ++t) {
    if (t + 1 < nt) stage((t + 1) & 1, (t + 1) * 32);
    const __bf16* As = smem + (t & 1) * BUF;
    const __bf16* Bs = As + ASZ;
    bf16x8 af[FM], bfr[FN];
#pragma unroll
    for (int mi = 0; mi < FM; ++mi)
      af[mi] = *(const bf16x8*)&As[(wm * (BM / 2) + mi * 16 + l15) * 32 + (l4 ^ sw) * 8];
#pragma unroll
    for (int ni = 0; ni < FN; ++ni)
      bfr[ni] = *(const bf16x8*)&Bs[(wn * (BN / 2) + ni * 16 + l15) * 32 + (l4 ^ sw) * 8];
#pragma unroll
    for (int mi = 0; mi < FM; ++mi)
#pragma unroll
      for (int ni = 0; ni < FN; ++ni)
        acc[mi][ni] = __builtin_amdgcn_mfma_f32_16x16x32_bf16(af[mi], bfr[ni], acc[mi][ni], 0, 0, 0);
    __syncthreads();  // t+1 loads drained; buf[t&1] reads done before overwrite
  }
}

// ---------------------------------------------------------------------------
// GEMM core (fp8 x fp8, BK=64, XOR-swizzled, 2-phase double-buffer):
// R12/R14-verified (VGPR 80-84 on k_gemm_s).
// ---------------------------------------------------------------------------
template <int BM, int BN>
__device__ __forceinline__ void gemm_core_fp8_db(
    const unsigned char* __restrict__ A, const unsigned char* __restrict__ Bt,
    int K, int m0, int n0, unsigned char* smem,
    f32x4 (&acc)[BM / 32][BN / 32])
{
  constexpr int FM = BM / 32, FN = BN / 32;
  constexpr int ASZ = (BM / 64) * 4096;   // A tile bytes (BM x 64)
  constexpr int BSZ = (BN / 64) * 4096;
  constexpr int BUF = ASZ + BSZ;
  const int tid = threadIdx.x;
  const int lane = tid & 63;
  const int wave = tid >> 6;
  const int wm = wave >> 1, wn = wave & 1;
  const int l15 = lane & 15, l4 = lane >> 4;
  const int sw = (l15 >> 1) & 3;
  const int h8 = (l4 & 1) * 8;      // 8B half within a 16B chunk
  const int nt = K >> 6;

  auto stage = [&](int b, int kt) {
    unsigned char* As_ = smem + b * BUF;
    unsigned char* Bs_ = As_ + ASZ;
#pragma unroll
    for (int i = 0; i < BM / 64; ++i) {
      int ci = i * 256 + tid;
      int row = ci >> 2, kc = ci & 3;
      int kcs = (kc ^ ((row >> 1) & 3)) * 16;  // swizzled 16B source chunk
      GLDS(A + (size_t)(m0 + row) * K + kt + kcs, As_ + i * 4096 + wave * 1024);
    }
#pragma unroll
    for (int i = 0; i < BN / 64; ++i) {
      int ci = i * 256 + tid;
      int row = ci >> 2, kc = ci & 3;
      int kcs = (kc ^ ((row >> 1) & 3)) * 16;
      GLDS(Bt + (size_t)(n0 + row) * K + kt + kcs, Bs_ + i * 4096 + wave * 1024);
    }
  };

  stage(0, 0);
  __syncthreads();                       // tile 0 valid
  for (int t = 0; t < nt; ++t) {
    if (t + 1 < nt) stage((t + 1) & 1, (t + 1) * 64);
    const unsigned char* As = smem + (t & 1) * BUF;
    const unsigned char* Bs = As + ASZ;
    long long af[FM][2], bfr[FN][2];
#pragma unroll
    for (int mi = 0; mi < FM; ++mi) {
      int row = wm * (BM / 2) + mi * 16 + l15;
#pragma unroll
      for (int j = 0; j < 2; ++j) {
        int G = j * 2 + (l4 >> 1);           // global 16B-chunk index
        af[mi][j] = *(const long long*)&As[row * 64 + ((G ^ sw) << 4) + h8];
      }
    }
#pragma unroll
    for (int ni = 0; ni < FN; ++ni) {
      int row = wn * (BN / 2) + ni * 16 + l15;
#pragma unroll
      for (int j = 0; j < 2; ++j) {
        int G = j * 2 + (l4 >> 1);
        bfr[ni][j] = *(const long long*)&Bs[row * 64 + ((G ^ sw) << 4) + h8];
      }
    }
#pragma unroll
    for (int mi = 0; mi < FM; ++mi)
#pragma unroll
      for (int ni = 0; ni < FN; ++ni) {
        f32x4 c = acc[mi][ni];
        c = __builtin_amdgcn_mfma_f32_16x16x32_fp8_fp8(af[mi][0], bfr[ni][0], c, 0, 0, 0);
        c = __builtin_amdgcn_mfma_f32_16x16x32_fp8_fp8(af[mi][1], bfr[ni][1], c, 0, 0, 0);
        acc[mi][ni] = c;
      }
    __syncthreads();  // t+1 loads drained; buf[t&1] reads done before overwrite
  }
}

// ---------------------------------------------------------------------------
// GEMM core (MX fp8, 32x32x64, scale=1.0, 3-buffer COUNTED-VMCNT pipeline):
// per tile: stage(t+2) -> s_waitcnt vmcnt(8) -> s_barrier -> ds_read+MFMA ->
// s_barrier.  (R18-verified, neutral-vs-dbuf but correct; PV is HBM-floor.)
// A-operand: lane l holds row (l&31), k-bytes [ (l>>5)*32 , +32 ).
// C/D (m74/m101): col = lane&31, row = (r&3)+8*(r>>2)+4*(l>>5).
// ---------------------------------------------------------------------------
template <int BM, int BN>
__device__ __forceinline__ void gemm_core_mx32_p3(
    const unsigned char* __restrict__ A, const unsigned char* __restrict__ Bt,
    int K, int m0, int n0, unsigned char* smem,
    f32x16 (&acc)[BM / 64][BN / 64])
{
  constexpr int FM = BM / 64, FN = BN / 64;
  constexpr int ASZ = (BM / 64) * 4096;
  constexpr int BSZ = (BN / 64) * 4096;
  constexpr int BUF = ASZ + BSZ;
  const int tid = threadIdx.x;
  const int lane = tid & 63;
  const int wave = tid >> 6;
  const int wm = wave >> 1, wn = wave & 1;
  const int l31 = lane & 31, h = lane >> 5;   // h: k-block of 32 bytes
  const int nt = K >> 6;

  auto stage = [&](int b, int t) {
    const int kt = t * 64;
    unsigned char* As_ = smem + b * BUF;
    unsigned char* Bs_ = As_ + ASZ;
#pragma unroll
    for (int i = 0; i < BM / 64; ++i) {
      int ci = i * 256 + tid;
      int row = ci >> 2, kc = ci & 3;
      int kcs = (kc ^ ((row >> 1) & 3)) * 16;
      GLDS(A + (size_t)(m0 + row) * K + kt + kcs, As_ + i * 4096 + wave * 1024);
    }
#pragma unroll
    for (int i = 0; i < BN / 64; ++i) {
      int ci = i * 256 + tid;
      int row = ci >> 2, kc = ci & 3;
      int kcs = (kc ^ ((row >> 1) & 3)) * 16;
      GLDS(Bt + (size_t)(n0 + row) * K + kt + kcs, Bs_ + i * 4096 + wave * 1024);
    }
  };

  stage(0, 0);
  stage(1, 1);
  int cb = 0, sb = 2;                    // compute buffer / stage buffer
  for (int t = 0; t < nt; ++t) {
    if (t + 2 < nt) stage(sb, t + 2);
    // Drain own stage-t loads; keep stages t+1 (and t+2 if issued) in flight.
    if (t + 2 < nt)      asm volatile("s_waitcnt vmcnt(8)" ::: "memory");
    else if (t + 1 < nt) asm volatile("s_waitcnt vmcnt(4)" ::: "memory");
    else                 asm volatile("s_waitcnt vmcnt(0)" ::: "memory");
    __builtin_amdgcn_s_barrier();        // all waves' t-loads landed
    __builtin_amdgcn_sched_barrier(0);
    const unsigned char* As = smem + cb * BUF;
    const unsigned char* Bs = As + ASZ;
    i32x8 af[FM], bfr[FN];
#pragma unroll
    for (int mi = 0; mi < FM; ++mi) {
      int row = wm * (BM / 2) + mi * 32 + l31;
      int s = (row >> 1) & 3;
      int c0 = (2 * h) ^ s, c1 = (2 * h + 1) ^ s;   // two 16B chunks = 32B of k
      uint4 u0 = *(const uint4*)&As[row * 64 + c0 * 16];
      uint4 u1 = *(const uint4*)&As[row * 64 + c1 * 16];
      af[mi][0] = (int)u0.x; af[mi][1] = (int)u0.y; af[mi][2] = (int)u0.z; af[mi][3] = (int)u0.w;
      af[mi][4] = (int)u1.x; af[mi][5] = (int)u1.y; af[mi][6] = (int)u1.z; af[mi][7] = (int)u1.w;
    }
#pragma unroll
    for (int ni = 0; ni < FN; ++ni) {
      int row = wn * (BN / 2) + ni * 32 + l31;
      int s = (row >> 1) & 3;
      int c0 = (2 * h) ^ s, c1 = (2 * h + 1) ^ s;
      uint4 u0 = *(const uint4*)&Bs[row * 64 + c0 * 16];
      uint4 u1 = *(const uint4*)&Bs[row * 64 + c1 * 16];
      bfr[ni][0] = (int)u0.x; bfr[ni][1] = (int)u0.y; bfr[ni][2] = (int)u0.z; bfr[ni][3] = (int)u0.w;
      bfr[ni][4] = (int)u1.x; bfr[ni][5] = (int)u1.y; bfr[ni][6] = (int)u1.z; bfr[ni][7] = (int)u1.w;
    }
#pragma unroll
    for (int mi = 0; mi < FM; ++mi)
#pragma unroll
      for (int ni = 0; ni < FN; ++ni)
        acc[mi][ni] = __builtin_amdgcn_mfma_scale_f32_32x32x64_f8f6f4(
            af[mi], bfr[ni], acc[mi][ni],
            0, 0,                       // cbsz/blgp = fp8 e4m3
            0, 0x7f7f7f7f,              // scale_a: e8m0 = 1.0
            0, 0x7f7f7f7f);             // scale_b: e8m0 = 1.0
    __builtin_amdgcn_sched_barrier(0);   // ds_reads complete before barrier
    __builtin_amdgcn_s_barrier();        // readers of buf cb done; cb is the
    __builtin_amdgcn_sched_barrier(0);   // buffer staged at iter t+1
    cb = (cb == 2) ? 0 : cb + 1;
    sb = (sb == 2) ? 0 : sb + 1;
  }
}

// fp8 16x16 C/D layout (measured m89/m91): col = lane&15, row = (lane>>4)*4 + reg.

// ---------------------------------------------------------------------------
// QKV GEMM: X[16384][512] @ Wqkv^T.  All outputs staged in LDS and written
// as coalesced 16B chunks: q8/k8 as [token][c] rows, v transposed to
// vt8[b][c][n] rows.  Bias folded into the staging conversion.  (R15-verified)
// ---------------------------------------------------------------------------
__global__ __launch_bounds__(256) void k_gemm_qkv(
    const __bf16* __restrict__ X, const __bf16* __restrict__ Wt,
    const float* __restrict__ bias, unsigned char* __restrict__ q8,
    unsigned char* __restrict__ k8, unsigned char* __restrict__ vt8)
{
  __shared__ __align__(16) __bf16 smem[2 * (128 * 32 + 128 * 32)];  // 32 KB dbuf
  f32x4 acc[4][4];
#pragma unroll
  for (int i = 0; i < 4; ++i)
#pragma unroll
    for (int j = 0; j < 4; ++j)
#pragma unroll
      for (int r = 0; r < 4; ++r) acc[i][j][r] = 0.f;
  const int m0 = blockIdx.x * 128, n0 = blockIdx.y * 128;
  gemm_core_db<128, 128>(X, Wt, 512, m0, n0, smem, acc);

  const int lane = threadIdx.x & 63, wave = threadIdx.x >> 6;
  const int wm = wave >> 1, wn = wave & 1, l15 = lane & 15, l4 = lane >> 4;

  // Stage the 128x128 fp8 patch in LDS (stride 144), then store coalesced.
  unsigned char* t8 = (unsigned char*)smem;  // 128*144 = 18432 B <= 32768
  if (blockIdx.y < 8) {
    // q or k: patch[token_local][c_local], no transpose
#pragma unroll
    for (int mi = 0; mi < 4; ++mi)
#pragma unroll
      for (int ni = 0; ni < 4; ++ni) {
        int lcol = wn * 64 + ni * 16 + l15;
        float bb = bias[n0 + lcol];
#pragma unroll
        for (int r = 0; r < 4; ++r) {
          int lrow = wm * 64 + mi * 16 + l4 * 4 + r;
          t8[lrow * 144 + lcol] = f2fp8(acc[mi][ni][r] + bb);
        }
      }
    __syncthreads();
    unsigned char* dst = (blockIdx.y < 4) ? q8 : k8;
    const int c0 = (blockIdx.y < 4) ? n0 : n0 - 512;
#pragma unroll
    for (int j = 0; j < 4; ++j) {
      int idx = j * 256 + threadIdx.x;
      int crow = idx >> 3, ccol = (idx & 7) * 16;
      uint4 v = *(const uint4*)&t8[crow * 144 + ccol];
      *(uint4*)&dst[(size_t)(m0 + crow) * 512 + c0 + ccol] = v;
    }
  } else {
    // v: patch transposed to [c_local][token_local]
#pragma unroll
    for (int mi = 0; mi < 4; ++mi)
#pragma unroll
      for (int ni = 0; ni < 4; ++ni) {
        int c_l = wn * 64 + ni * 16 + l15;
        float bb = bias[n0 + c_l];
#pragma unroll
        for (int r = 0; r < 4; ++r) {
          int n_l = wm * 64 + mi * 16 + l4 * 4 + r;
          t8[c_l * 144 + n_l] = f2fp8(acc[mi][ni][r] + bb);
        }
      }
    __syncthreads();
    const int b = m0 >> 12, nst = m0 & 4095;
    const int c0 = n0 - 1024;
#pragma unroll
    for (int j = 0; j < 4; ++j) {
      int idx = j * 256 + threadIdx.x;
      int crow = idx >> 3, ccol = (idx & 7) * 16;
      uint4 v = *(const uint4*)&t8[crow * 144 + ccol];
      *(uint4*)&vt8[((size_t)b * 512 + c0 + crow) * 4096 + nst + ccol] = v;
    }
  }
}

// ---------------------------------------------------------------------------
// Scores GEMM (fp8 x fp8, BK=64, 2-phase dbuf) + max-free softmax numerator,
// batched over z: P[b][n][m] = exp2(q'.k) stored fp8 e4m3 (log2e folded into
// q' at prep); lsum fp32 row sums.  exp2 via __builtin_amdgcn_exp2f = one
// v_exp_f32 per element.  Epilogue: ONE-pass staging into 128x144 LDS tile,
// 16B-coalesced stores.
// ---------------------------------------------------------------------------
__global__ __launch_bounds__(256) void k_gemm_s(
    const unsigned char* __restrict__ qall, const unsigned char* __restrict__ kall,
    unsigned char* __restrict__ S8all, float* __restrict__ lsum)
{
  __shared__ __align__(16) unsigned char smem[32768];  // 2 x (8KB As + 8KB Bs)
  f32x4 acc[4][4];
#pragma unroll
  for (int i = 0; i < 4; ++i)
#pragma unroll
    for (int j = 0; j < 4; ++j)
#pragma unroll
      for (int r = 0; r < 4; ++r) acc[i][j][r] = 0.f;

  // supertile swizzle: 1024 blocks/batch -> 16 groups of 64 (8x8)
  const int b = blockIdx.z;
  const int flat = blockIdx.x + (blockIdx.y << 5);
  const int gx = flat & 7, gy = (flat >> 3) & 7, grp = flat >> 6;
  const int bx = (grp & 3) * 8 + gx, by = (grp >> 2) * 8 + gy;
  const int m0 = bx * 128, n0 = by * 128;

  const unsigned char* q = qall + (size_t)b * 4096 * 512;
  const unsigned char* k = kall + (size_t)b * 4096 * 512;
  unsigned char* S8 = S8all + (size_t)b * 4096 * 4096;
  gemm_core_fp8_db<128, 128>(q, k, 512, m0, n0, smem, acc);

  const int lane = threadIdx.x & 63, wave = threadIdx.x >> 6;
  const int wm = wave >> 1, wn = wave & 1, l15 = lane & 15, l4 = lane >> 4;

  // exp2 in place + fp32 row-sum atomics (pre-fp8-rounding; unbiased)
#pragma unroll
  for (int mi = 0; mi < 4; ++mi) {
    float rsum[4] = {0.f, 0.f, 0.f, 0.f};
#pragma unroll
    for (int ni = 0; ni < 4; ++ni)
#pragma unroll
      for (int r = 0; r < 4; ++r) {
        float p = __builtin_amdgcn_exp2f(acc[mi][ni][r]);  // raw v_exp_f32
        acc[mi][ni][r] = p;
        rsum[r] += p;
      }
#pragma unroll
    for (int r = 0; r < 4; ++r) {
#pragma unroll
      for (int off = 1; off < 16; off <<= 1) rsum[r] += __shfl_xor(rsum[r], off, 64);
      if (l15 == 0) {
        int grow = m0 + wm * 64 + mi * 16 + l4 * 4 + r;
        atomicAdd(&lsum[b * 4096 + grow], rsum[r]);
      }
    }
  }

  // One-pass staging: all waves convert into t8[128][144], then store.
  unsigned char* t8 = smem;  // 128*144 = 18432 B <= 32768
#pragma unroll
  for (int mi = 0; mi < 4; ++mi)
#pragma unroll
    for (int ni = 0; ni < 4; ++ni) {
      int lcol = wn * 64 + ni * 16 + l15;
#pragma unroll
      for (int r = 0; r < 4; ++r) {
        int lrow = wm * 64 + mi * 16 + l4 * 4 + r;
        t8[lrow * 144 + lcol] = f2fp8(acc[mi][ni][r]);
      }
    }
  __syncthreads();
  // store 128 rows x 128 B: 1024 chunks of 16B, 4 per thread
#pragma unroll
  for (int j = 0; j < 4; ++j) {
    int idx = j * 256 + threadIdx.x;
    int crow = idx >> 3, ccol = (idx & 7) * 16;
    uint4 v = *(const uint4*)&t8[crow * 144 + ccol];
    *(uint4*)&S8[(size_t)(m0 + crow) * 4096 + n0 + ccol] = v;
  }
}

// ---------------------------------------------------------------------------
// PV GEMM (MX fp8 32x32x64, BK=64, 3-buffer counted-vmcnt pipeline, 128x128),
// batched over z: O[b,n,c] = (sum_m P[b,n,m] * vt[b,c,m]) / l[b,n].
// ---------------------------------------------------------------------------
__global__ __launch_bounds__(256) void k_gemm_pv(
    const unsigned char* __restrict__ S8all, const unsigned char* __restrict__ vt8all,
    const float* __restrict__ lsum, __bf16* __restrict__ attn)
{
  __shared__ __align__(16) unsigned char smem[49152];  // 3 x (8KB As + 8KB Bs)
  f32x16 acc[2][2];
#pragma unroll
  for (int i = 0; i < 2; ++i)
#pragma unroll
    for (int j = 0; j < 2; ++j)
#pragma unroll
      for (int r = 0; r < 16; ++r) acc[i][j][r] = 0.f;
  const int b = blockIdx.z;
  const unsigned char* P = S8all + (size_t)b * 4096 * 4096;
  const unsigned char* V = vt8all + (size_t)b * 512 * 4096;
  __bf16* O = attn + (size_t)b * 4096 * 512;
  const int m0 = blockIdx.x * 128, n0 = blockIdx.y * 128;
  gemm_core_mx32_p3<128, 128>(P, V, 4096, m0, n0, smem, acc);

  const int lane = threadIdx.x & 63, wave = threadIdx.x >> 6;
  const int wm = wave >> 1, wn = wave & 1, l31 = lane & 31, h = lane >> 5;
#pragma unroll
  for (int mi = 0; mi < 2; ++mi)
#pragma unroll
    for (int ni = 0; ni < 2; ++ni) {
      int gcol = n0 + wn * 64 + ni * 32 + l31;
#pragma unroll
      for (int r = 0; r < 16; ++r) {
        int grow = m0 + wm * 64 + mi * 32 + (r & 3) + 8 * (r >> 2) + 4 * h;
        float inv = 1.f / lsum[b * 4096 + grow];
        O[(size_t)grow * 512 + gcol] = (__bf16)(acc[mi][ni][r] * inv);
      }
    }
}

// ---------------------------------------------------------------------------
// Output projection + bias + residual, fp32 store to d_out.
// ---------------------------------------------------------------------------
__global__ __launch_bounds__(256) void k_gemm_out(
    const __bf16* __restrict__ A, const __bf16* __restrict__ Wot,
    const float* __restrict__ bo, const float* __restrict__ resid, float* __restrict__ out)
{
  __shared__ __align__(16) __bf16 smem[2 * (128 * 32 + 128 * 32)];  // 32 KB dbuf
  f32x4 acc[4][4];
#pragma unroll
  for (int i = 0; i < 4; ++i)
#pragma unroll
    for (int j = 0; j < 4; ++j)
#pragma unroll
      for (int r = 0; r < 4; ++r) acc[i][j][r] = 0.f;
  const int m0 = blockIdx.x * 128, n0 = blockIdx.y * 128;
  gemm_core_db<128, 128>(A, Wot, 512, m0, n0, smem, acc);

  const int lane = threadIdx.x & 63, wave = threadIdx.x >> 6;
  const int wm = wave >> 1, wn = wave & 1, l15 = lane & 15, l4 = lane >> 4;
#pragma unroll
  for (int mi = 0; mi < 4; ++mi)
#pragma unroll
    for (int ni = 0; ni < 4; ++ni) {
      int gcol = n0 + wn * 64 + ni * 16 + l15;
      float bb = bo[gcol];
#pragma unroll
      for (int r = 0; r < 4; ++r) {
        int grow = m0 + wm * 64 + mi * 16 + l4 * 4 + r;
        size_t idx = (size_t)grow * 512 + gcol;
        out[idx] = acc[mi][ni][r] + bb + resid[idx];
      }
    }
}

// ---------------------------------------------------------------------------
extern "C" void kernel_launch(void* const* d_in, const int* in_sizes, int n_in,
                              void* d_out, int out_size, void* d_ws, size_t ws_size,
                              hipStream_t stream)
{
  const float* x     = (const float*)d_in[0];
  const float* gamma = (const float*)d_in[1];
  const float* beta  = (const float*)d_in[2];
  const float* wq    = (const float*)d_in[3];
  const float* bq    = (const float*)d_in[4];
  const float* wk    = (const float*)d_in[5];
  const float* bk    = (const float*)d_in[6];
  const float* wv    = (const float*)d_in[7];
  const float* bv    = (const float*)d_in[8];
  const float* wo    = (const float*)d_in[9];
  const float* bo    = (const float*)d_in[10];
  float* out = (float*)d_out;

  char* ws = (char*)d_ws;
  size_t off = 0;
  auto alloc = [&](size_t bytes) -> char* {
    char* p = ws + off;
    off += (bytes + 255) & ~(size_t)255;
    return p;
  };
  float*  gnp     = (float*)alloc(1024 * 4);
  float*  gnssp   = (float*)alloc(1024 * 4);
  __bf16* x16     = (__bf16*)alloc(16384ull * 512 * 2);   // 16 MB
  __bf16* wqkvt   = (__bf16*)alloc(1536ull * 512 * 2);    // 1.5 MB
  float*  biasqkv = (float*)alloc(1536 * 4);
  __bf16* wot     = (__bf16*)alloc(512ull * 512 * 2);     // 0.5 MB
  float*  lsum    = (float*)alloc(16384ull * 4);          // 64 KB row sums
  unsigned char* q8  = (unsigned char*)alloc(16384ull * 512);     // 8 MB fp8 Q
  unsigned char* k8  = (unsigned char*)alloc(16384ull * 512);     // 8 MB fp8 K
  unsigned char* vt8 = (unsigned char*)alloc(16384ull * 512);     // 8 MB fp8 V^T
  __bf16* attn    = (__bf16*)alloc(16384ull * 512 * 2);   // 16 MB
  unsigned char* S8 = (unsigned char*)alloc(4ull * 4096 * 4096);  // 64 MB fp8 exp(scores)
  // total ~122 MB

  k_pre<<<dim3(5191), dim3(256), 0, stream>>>(wq, bq, wk, bk, wv, bv, wo,
                                              wqkvt, biasqkv, wot, lsum,
                                              x, gnp, gnssp);
  k_norm<<<dim3(8192), dim3(256), 0, stream>>>(x, gnp, gnssp, gamma, beta, x16);
  k_gemm_qkv<<<dim3(128, 12), dim3(256), 0, stream>>>(x16, wqkvt, biasqkv, q8, k8, vt8);
  k_gemm_s<<<dim3(32, 32, 4), dim3(256), 0, stream>>>(q8, k8, S8, lsum);
  k_gemm_pv<<<dim3(32, 4, 4), dim3(256), 0, stream>>>(S8, vt8, lsum, attn);
  k_gemm_out<<<dim3(128, 4), dim3(256), 0, stream>>>(attn, wot, bo, x, out);
}